// Round 10
// baseline (217.692 us; speedup 1.0000x reference)
//
#include <hip/hip_runtime.h>
#include <stdint.h>

// Problem constants
#define BATCH 16384
#define INDIM 256
#define DDIM  128
#define NEXP  8
#define ROWS  32          // batch rows per block (2 row-tiles of 16)
#define THREADS 256       // 4 waves; wave wv = col-group cg (32 cols each)
#define NSTEP 96          // staging steps: (st, eb0, q) kt-pair granules

typedef __bf16 bfv8  __attribute__((ext_vector_type(8)));   // MFMA A/B frag: 8 bf16 = 4 VGPRs
typedef float  f32x4 __attribute__((ext_vector_type(4)));   // MFMA C/D frag

typedef __attribute__((address_space(1))) const void gas_void;
typedef __attribute__((address_space(3))) void las_void;

// ---------------------------------------------------------------------------
// Prep kernel (R7 version, unchanged): coalesced repack of Wa/Wb/Ws and gate
// matrices into bf16 MFMA B-fragment layout. Contract:
//   wp + g*4096 + nt*512 + lane*8 + j = (bf16) W_st[e*256 + kt*32 +
//     (lane>>4)*8 + j][nt*16 + (lane&15)],  g = st*64 + e*8 + kt.
// ---------------------------------------------------------------------------
__global__ void prep_kernel(const float* __restrict__ Wa, const float* __restrict__ Wb,
                            const float* __restrict__ Ws, const float* __restrict__ Ga,
                            const float* __restrict__ Gb, const float* __restrict__ Gs,
                            __bf16* __restrict__ wp, __bf16* __restrict__ gp) {
    __shared__ float ws[32 * 132];          // 32 rows x 128 cols, pad 4
    const int b = blockIdx.x, tid = threadIdx.x;
    if (b < 192) {
        const int st = b >> 6, e = (b >> 3) & 7, kt = b & 7;
        const float* W = (st == 0) ? Wa : (st == 1) ? Wb : Ws;
        const float* src = W + (size_t)(e * 256 + kt * 32) * 128;
#pragma unroll
        for (int k = 0; k < 4; k++) {
            int idx4 = tid + k * 256;
            f32x4 v = *(const f32x4*)(src + (size_t)idx4 * 4);
            int row = idx4 >> 5;
            int col = (idx4 & 31) << 2;
            ws[row * 132 + col + 0] = v[0];
            ws[row * 132 + col + 1] = v[1];
            ws[row * 132 + col + 2] = v[2];
            ws[row * 132 + col + 3] = v[3];
        }
        __syncthreads();
        __bf16* o = wp + ((size_t)b << 12);
#pragma unroll
        for (int h2 = 0; h2 < 2; h2++) {
            int base = tid * 2 + h2;
            int nt = base >> 6, lane = base & 63;
            int d  = nt * 16 + (lane & 15);
            int i0 = (lane >> 4) * 8;
            bfv8 ov;
#pragma unroll
            for (int j = 0; j < 8; j++) ov[j] = (__bf16)ws[(i0 + j) * 132 + d];
            *(bfv8*)(o + (size_t)base * 8) = ov;
        }
    } else {
        int t2 = (b - 192) * 256 + tid;
        int lane = t2 & 63, nt = (t2 >> 6) & 3, kt = t2 >> 8;
        int g  = nt * 16 + (lane & 15);
        int k0 = kt * 32 + (lane >> 4) * 8;
        __bf16* o = gp + (size_t)t2 * 8;
#pragma unroll
        for (int j = 0; j < 8; j++) {
            int k = k0 + j;
            float v = 0.f;
            if (g < 16)      v = Ga[g * 256 + k];
            else if (g < 32) v = Gb[(g - 16) * 256 + k];
            else if (g < 56) v = Gs[(g - 32) * 256 + k];
            o[j] = (__bf16)v;
        }
    }
}

// Load A fragments (2 row-tiles x 8 k-tiles), fp32->bf16, nontemporal.
__device__ __forceinline__ void load_afr(const float* __restrict__ x, int rb,
                                         int l16, int quad, bfv8 afr[2][8]) {
#pragma unroll
    for (int mt = 0; mt < 2; mt++) {
        const float* xr = x + (size_t)(rb + mt * 16 + l16) * INDIM;
#pragma unroll
        for (int kt = 0; kt < 8; kt++) {
            const f32x4* p = (const f32x4*)(xr + kt * 32 + quad * 8);
            f32x4 lo = __builtin_nontemporal_load(p);
            f32x4 hi = __builtin_nontemporal_load(p + 1);
            bfv8 a;
            a[0] = (__bf16)lo[0]; a[1] = (__bf16)lo[1]; a[2] = (__bf16)lo[2]; a[3] = (__bf16)lo[3];
            a[4] = (__bf16)hi[0]; a[5] = (__bf16)hi[1]; a[6] = (__bf16)hi[2]; a[7] = (__bf16)hi[3];
            afr[mt][kt] = a;
        }
    }
}

// Stage one kt-pair granule (4 KB: the 2 x 1024-elem regions wave cg reads
// for kt = q*2, q*2+1) into this wave's private slot. 4 x global_load_lds.
// No other wave touches this LDS -> no barrier needed, per-wave vmcnt only.
__device__ __forceinline__ void stage_step(const __bf16* __restrict__ wp,
                                           __bf16* pbuf, int st, int eb, int q,
                                           int slot, int cg, int lane) {
    const __bf16* src = wp + (((size_t)(st * 64 + eb * 8 + q * 2)) << 12)
                           + (cg << 10) + (lane << 3);
    __bf16* d = pbuf + (slot << 11);
#pragma unroll
    for (int j = 0; j < 2; j++)          // kt-slab j (stride 4096 elems in wp)
#pragma unroll
        for (int sub = 0; sub < 2; sub++) // 512-elem sub-region
            __builtin_amdgcn_global_load_lds(
                (gas_void*)(src + (j << 12) + (sub << 9)),
                (las_void*)(d + (j << 10) + (sub << 9)), 16, 0, 0);
}

// ---------------------------------------------------------------------------
// Main fused kernel R8. Grid 512 x 256 threads (4 waves). LDS = 40960 B ->
// 4 blocks/CU = 16 waves/CU = 4 waves/SIMD (2x all prior rounds; R4-R7 all
// ran 2/SIMD and all hit the same ~85us wall with every pipe <15% busy ->
// latency-exposure theory: TLP, not ILP, is the missing hiding mechanism).
// Phase 2 is BARRIER-FREE: each wave stages only the 4KB/step its own cg
// reads into a private double-buffered LDS slot, with counted vmcnt
// (6 at q==0 where 2 bias loads interleave, else 4; 0 only at the tail).
// vmcnt FIFO audit (steady state): wait point sees [stage(s) 4 | (bias 2) |
// stage(s+1) 4] -> vmcnt(6|4) retires exactly stage(s). st-boundary adds 16
// x-loads to the FIFO -> the q==0 wait over-drains them (2x per kernel, ~us).
// ---------------------------------------------------------------------------
__launch_bounds__(THREADS, 4)
__global__ void ple_kernel(const float* __restrict__ xa, const float* __restrict__ xb,
                           const float* __restrict__ xs,
                           const float* __restrict__ ba, const float* __restrict__ bb,
                           const float* __restrict__ bs,
                           const __bf16* __restrict__ wp, const __bf16* __restrict__ gp,
                           float* __restrict__ out) {
    __shared__ __align__(16) unsigned char smem[40960];
    __bf16* ring = (__bf16*)smem;               // 4 waves x 8KB private dbuf
    float*  wT   = (float*)(smem + 32768);      // 8KB softmax weights [gate][row]
    float*  lgt  = (float*)smem;                // 8KB logits, phase-1 alias of ring

    const int tid  = threadIdx.x;
    const int wv   = tid >> 6;        // wave id 0..3 == col-group cg
    const int lane = tid & 63;
    const int cg   = wv;
    const int quad = lane >> 4;
    const int l16  = lane & 15;
    const int rb   = blockIdx.x * ROWS;
    const int rot  = (blockIdx.x >> 3) & 7;     // keep R7's +4% rotation

    bfv8 afr[2][8];

    // ---------------- Phase 1: gate logits via MFMA ----------------
    {
        const float* x = (cg == 0) ? xa : (cg == 1) ? xb : xs;  // wave-uniform
        load_afr(x, rb, l16, quad, afr);
        f32x4 acc1[2];
#pragma unroll
        for (int mt = 0; mt < 2; mt++) { f32x4 z = {0.f, 0.f, 0.f, 0.f}; acc1[mt] = z; }
#pragma unroll
        for (int kt = 0; kt < 8; kt++) {
            bfv8 gfr = *(const bfv8*)(gp + ((size_t)(kt * 4 + cg) * 64 + lane) * 8);
#pragma unroll
            for (int mt = 0; mt < 2; mt++)
                acc1[mt] = __builtin_amdgcn_mfma_f32_16x16x32_bf16(afr[mt][kt], gfr, acc1[mt], 0, 0, 0);
        }
#pragma unroll
        for (int mt = 0; mt < 2; mt++)
#pragma unroll
            for (int r = 0; r < 4; r++)
                lgt[(mt * 16 + quad * 4 + r) * 64 + cg * 16 + l16] = acc1[mt][r];
    }
    __syncthreads();

    // ---------------- softmax per row (32 rows) ----------------
    if (tid < ROWS) {
        const float* L = lgt + tid * 64;
#pragma unroll
        for (int gi = 0; gi < 3; gi++) {
            const int base = (gi == 0) ? 0 : (gi == 1 ? 16 : 32);
            const int cnt  = (gi == 2) ? 24 : 16;
            float m = -1e30f;
            for (int k = 0; k < cnt; k++) m = fmaxf(m, L[base + k]);
            float s = 0.f;
            for (int k = 0; k < cnt; k++) s += __expf(L[base + k] - m);
            float inv = 1.f / s;
            for (int k = 0; k < cnt; k++) wT[(base + k) * ROWS + tid] = __expf(L[base + k] - m) * inv;
        }
    }
    __syncthreads();   // after this: lgt dead -> ring reuse safe; wT stable (read-only)

    // ---------------- Phase 2: experts, barrier-free per-wave pipeline ------
    __bf16* pbuf = ring + (wv << 12);   // this wave's 8KB (2 slots x 4KB)

    float o[3][2][2][4];
#pragma unroll
    for (int oi = 0; oi < 3; oi++)
#pragma unroll
        for (int mt = 0; mt < 2; mt++)
#pragma unroll
            for (int ntl = 0; ntl < 2; ntl++)
#pragma unroll
                for (int r = 0; r < 4; r++) o[oi][mt][ntl][r] = 0.f;

#define FOLD(oi, gbase)                                                                 \
    {                                                                                   \
        _Pragma("unroll")                                                               \
        for (int mt = 0; mt < 2; mt++) {                                                \
            f32x4 gw4 = *(const f32x4*)(wT + (gbase + eb) * ROWS + mt * 16 + quad * 4); \
            _Pragma("unroll")                                                           \
            for (int ntl = 0; ntl < 2; ntl++)                                           \
                _Pragma("unroll")                                                       \
                for (int r = 0; r < 4; r++)                                             \
                    o[oi][mt][ntl][r] += gw4[r] * acc[mt][ntl][r];                      \
        }                                                                               \
    }

    // prologue: stage step 0 (st=0, eb0=0 -> eb=rot, q=0) into slot 0
    stage_step(wp, pbuf, 0, rot & 7, 0, 0, cg, lane);

#pragma unroll
    for (int st = 0; st < 3; st++) {
        const float* x    = (st == 0) ? xa : (st == 1) ? xb : xs;
        const float* bias = (st == 0) ? ba : (st == 1) ? bb : bs;
        load_afr(x, rb, l16, quad, afr);

#pragma unroll 1
        for (int eb0 = 0; eb0 < NEXP; eb0++) {
            const int eb = (eb0 + rot) & 7;
            float b0 = bias[eb * 128 + cg * 32 + l16];        // issued before stage(s+1)
            float b1 = bias[eb * 128 + cg * 32 + 16 + l16];   // -> drained by q>=1 waits

            f32x4 acc[2][2];
#pragma unroll
            for (int mt = 0; mt < 2; mt++)
#pragma unroll
                for (int ntl = 0; ntl < 2; ntl++) { f32x4 z = {0.f, 0.f, 0.f, 0.f}; acc[mt][ntl] = z; }

#pragma unroll
            for (int q = 0; q < 4; q++) {
                const int s = st * 32 + eb0 * 4 + q;
                if (s + 1 < NSTEP) {
                    const int s1 = s + 1, st1 = s1 >> 5, r1 = s1 & 31;
                    stage_step(wp, pbuf, st1, ((r1 >> 2) + rot) & 7, r1 & 3,
                               s1 & 1, cg, lane);
                    if (q == 0) asm volatile("s_waitcnt vmcnt(6)" ::: "memory");
                    else        asm volatile("s_waitcnt vmcnt(4)" ::: "memory");
                } else {
                    asm volatile("s_waitcnt vmcnt(0)" ::: "memory");
                }
                __builtin_amdgcn_sched_barrier(0);   // MIR fence: no hoist above wait

                const __bf16* pb = pbuf + ((s & 1) << 11);
                __builtin_amdgcn_s_setprio(1);
#pragma unroll
                for (int j = 0; j < 2; j++) {
                    const int kt = q * 2 + j;
                    bfv8 bv0 = *(const bfv8*)(pb + (j << 10) + ((size_t)lane << 3));
                    bfv8 bv1 = *(const bfv8*)(pb + (j << 10) + 512 + ((size_t)lane << 3));
                    acc[0][0] = __builtin_amdgcn_mfma_f32_16x16x32_bf16(afr[0][kt], bv0, acc[0][0], 0, 0, 0);
                    acc[1][0] = __builtin_amdgcn_mfma_f32_16x16x32_bf16(afr[1][kt], bv0, acc[1][0], 0, 0, 0);
                    acc[0][1] = __builtin_amdgcn_mfma_f32_16x16x32_bf16(afr[0][kt], bv1, acc[0][1], 0, 0, 0);
                    acc[1][1] = __builtin_amdgcn_mfma_f32_16x16x32_bf16(afr[1][kt], bv1, acc[1][1], 0, 0, 0);
                }
                __builtin_amdgcn_s_setprio(0);
            }

            // bias (per output column)
#pragma unroll
            for (int mt = 0; mt < 2; mt++)
#pragma unroll
                for (int r = 0; r < 4; r++) { acc[mt][0][r] += b0; acc[mt][1][r] += b1; }

            // gated fold. Gate table columns: a:0-15, b:16-31, s:32-55.
            if (st == 0)      { FOLD(0, 0);  FOLD(2, 32); }
            else if (st == 1) { FOLD(1, 16); FOLD(2, 40); }
            else              { FOLD(0, 8);  FOLD(1, 24); FOLD(2, 48); }
        }
    }
#undef FOLD

    // ---------------- epilogue: store 3 outputs (nontemporal) ----------------
#pragma unroll
    for (int oi = 0; oi < 3; oi++) {
        float* ob = out + (size_t)oi * BATCH * DDIM;
#pragma unroll
        for (int mt = 0; mt < 2; mt++)
#pragma unroll
            for (int r = 0; r < 4; r++) {
                int row = rb + mt * 16 + quad * 4 + r;
#pragma unroll
                for (int ntl = 0; ntl < 2; ntl++)
                    __builtin_nontemporal_store(o[oi][mt][ntl][r],
                        &ob[(size_t)row * DDIM + cg * 32 + ntl * 16 + l16]);
            }
    }
}

extern "C" void kernel_launch(void* const* d_in, const int* in_sizes, int n_in,
                              void* d_out, int out_size, void* d_ws, size_t ws_size,
                              hipStream_t stream) {
    const float* xa = (const float*)d_in[0];
    const float* xb = (const float*)d_in[1];
    const float* xs = (const float*)d_in[2];
    const float* Wa = (const float*)d_in[3];
    const float* ba = (const float*)d_in[4];
    const float* Wb = (const float*)d_in[5];
    const float* bb = (const float*)d_in[6];
    const float* Ws = (const float*)d_in[7];
    const float* bs = (const float*)d_in[8];
    const float* Ga = (const float*)d_in[9];
    const float* Gb = (const float*)d_in[10];
    const float* Gs = (const float*)d_in[11];

    __bf16* wp = (__bf16*)d_ws;                 // 1.5 MB packed expert weights
    __bf16* gp = wp + 3 * 8 * 8 * 8 * 64 * 8;   // 32 KB packed gate matrix

    prep_kernel<<<200, 256, 0, stream>>>(Wa, Wb, Ws, Ga, Gb, Gs, wp, gp);
    ple_kernel<<<BATCH / ROWS, THREADS, 0, stream>>>(xa, xb, xs, ba, bb, bs, wp, gp, (float*)d_out);
}

// Round 14
// 217.583 us; speedup vs baseline: 1.0005x; 1.0005x over previous
//
#include <hip/hip_runtime.h>
#include <stdint.h>

// Problem constants
#define BATCH 16384
#define INDIM 256
#define DDIM  128
#define NEXP  8
#define ROWS  64          // batch rows per block: 2 row-groups x (2 row-tiles of 16)
#define THREADS 512       // 8 waves = 2 row-groups x 4 col-groups
#define NSEQ  96          // staging intervals: (st, eb0, q) quarter-expert slabs
#define QSLAB 8192        // bf16 elems per quarter-expert slab (2 kt-slabs = 16 KB)

typedef __bf16 bfv8  __attribute__((ext_vector_type(8)));   // MFMA A/B frag: 8 bf16 = 4 VGPRs
typedef float  f32x4 __attribute__((ext_vector_type(4)));   // MFMA C/D frag

typedef __attribute__((address_space(1))) const void gas_void;
typedef __attribute__((address_space(3))) void las_void;

// ---------------------------------------------------------------------------
// Prep kernel (R7 version, unchanged, passing): coalesced repack of Wa/Wb/Ws
// and gate matrices into bf16 MFMA B-fragment layout. Contract:
//   wp + g*4096 + nt*512 + lane*8 + j = (bf16) W_st[e*256 + kt*32 +
//     (lane>>4)*8 + j][nt*16 + (lane&15)],  g = st*64 + e*8 + kt.
// ---------------------------------------------------------------------------
__global__ void prep_kernel(const float* __restrict__ Wa, const float* __restrict__ Wb,
                            const float* __restrict__ Ws, const float* __restrict__ Ga,
                            const float* __restrict__ Gb, const float* __restrict__ Gs,
                            __bf16* __restrict__ wp, __bf16* __restrict__ gp) {
    __shared__ float ws[32 * 132];          // 32 rows x 128 cols, pad 4
    const int b = blockIdx.x, tid = threadIdx.x;
    if (b < 192) {
        const int st = b >> 6, e = (b >> 3) & 7, kt = b & 7;
        const float* W = (st == 0) ? Wa : (st == 1) ? Wb : Ws;
        const float* src = W + (size_t)(e * 256 + kt * 32) * 128;
#pragma unroll
        for (int k = 0; k < 4; k++) {
            int idx4 = tid + k * 256;
            f32x4 v = *(const f32x4*)(src + (size_t)idx4 * 4);
            int row = idx4 >> 5;
            int col = (idx4 & 31) << 2;
            ws[row * 132 + col + 0] = v[0];
            ws[row * 132 + col + 1] = v[1];
            ws[row * 132 + col + 2] = v[2];
            ws[row * 132 + col + 3] = v[3];
        }
        __syncthreads();
        __bf16* o = wp + ((size_t)b << 12);
#pragma unroll
        for (int h2 = 0; h2 < 2; h2++) {
            int base = tid * 2 + h2;
            int nt = base >> 6, lane = base & 63;
            int d  = nt * 16 + (lane & 15);
            int i0 = (lane >> 4) * 8;
            bfv8 ov;
#pragma unroll
            for (int j = 0; j < 8; j++) ov[j] = (__bf16)ws[(i0 + j) * 132 + d];
            *(bfv8*)(o + (size_t)base * 8) = ov;
        }
    } else {
        int t2 = (b - 192) * 256 + tid;
        int lane = t2 & 63, nt = (t2 >> 6) & 3, kt = t2 >> 8;
        int g  = nt * 16 + (lane & 15);
        int k0 = kt * 32 + (lane >> 4) * 8;
        __bf16* o = gp + (size_t)t2 * 8;
#pragma unroll
        for (int j = 0; j < 8; j++) {
            int k = k0 + j;
            float v = 0.f;
            if (g < 16)      v = Ga[g * 256 + k];
            else if (g < 32) v = Gb[(g - 16) * 256 + k];
            else if (g < 56) v = Gs[(g - 32) * 256 + k];
            o[j] = (__bf16)v;
        }
    }
}

// Load A fragments (2 row-tiles x 8 k-tiles), fp32->bf16, nontemporal (R7).
__device__ __forceinline__ void load_afr(const float* __restrict__ x, int rb,
                                         int l16, int quad, bfv8 afr[2][8]) {
#pragma unroll
    for (int mt = 0; mt < 2; mt++) {
        const float* xr = x + (size_t)(rb + mt * 16 + l16) * INDIM;
#pragma unroll
        for (int kt = 0; kt < 8; kt++) {
            const f32x4* p = (const f32x4*)(xr + kt * 32 + quad * 8);
            f32x4 lo = __builtin_nontemporal_load(p);
            f32x4 hi = __builtin_nontemporal_load(p + 1);
            bfv8 a;
            a[0] = (__bf16)lo[0]; a[1] = (__bf16)lo[1]; a[2] = (__bf16)lo[2]; a[3] = (__bf16)lo[3];
            a[4] = (__bf16)hi[0]; a[5] = (__bf16)hi[1]; a[6] = (__bf16)hi[2]; a[7] = (__bf16)hi[3];
            afr[mt][kt] = a;
        }
    }
}

// Stage one 16KB quarter-expert slab (physical index qslab, units of 8192
// elems) into ring slot. 8 waves x 2 glls of 1KB (LDS dest = wave-uniform
// base + lane*16B, HW rule). Wave wv covers slab elems [wv*1024, +1024).
__device__ __forceinline__ void stage_q(const __bf16* __restrict__ wp,
                                        __bf16* ring, int qslab, int slot,
                                        int wv, int lane) {
    const __bf16* src = wp + ((size_t)qslab << 13) + (wv << 10) + (lane << 3);
    __bf16* dst = ring + (slot << 13) + (wv << 10);
#pragma unroll
    for (int i = 0; i < 2; i++)
        __builtin_amdgcn_global_load_lds((gas_void*)(src + (i << 9)),
                                         (las_void*)(dst + (i << 9)), 16, 0, 0);
}

// Rotation (R7, +4-5% proven): interval s = st*32 + eb0*4 + q -> physical
// quarter-slab; expert processed at eb0 is (eb0+rot)&7.
//   s>>2 = st*8 + eb0 (q floors away); &7 -> eb0.
__device__ __forceinline__ int qslab_of(int s, int rot) {
    int st = s >> 5;
    int eb = (((s >> 2) & 7) + rot) & 7;
    return (st << 5) | (eb << 2) | (s & 3);
}

// ---------------------------------------------------------------------------
// Main fused kernel R10 = R7 (passing, 83us) with MINIMAL delta for 2x TLP:
//   (1) staging granule halved 32KB->16KB (NSEQ 48->96): ring 64KB->32KB,
//       so LDS = 32 ring + 16 lgt + 16 wT = 64KB exactly. No aliasing.
//   (2) __launch_bounds__(512,2)->(512,4): 2 blocks/CU = 16 waves/CU =
//       4 waves/SIMD (VGPR measured 96 <= 128 cap).
// All indexing/decomposition identical to R7: wave (rg,cg), rows
// [rb+rg*32,+32), cols [cg*32,+32); depth-1 prefetch; plain __syncthreads
// per interval (R5/R6 A/B: plain-barrier count is a non-factor).
// Theory: per-CU staging rate scales with resident waves (m97: 51 GB/s/CU
// @12 waves vs our ~20 @8); 2 independent blocks/CU also overlap each
// other's barrier stalls (m114). Total weight traffic unchanged (384MB).
// ---------------------------------------------------------------------------
__launch_bounds__(THREADS, 4)
__global__ void ple_kernel(const float* __restrict__ xa, const float* __restrict__ xb,
                           const float* __restrict__ xs,
                           const float* __restrict__ ba, const float* __restrict__ bb,
                           const float* __restrict__ bs,
                           const __bf16* __restrict__ wp, const __bf16* __restrict__ gp,
                           float* __restrict__ out) {
    __shared__ __bf16 ring[2 * QSLAB];      // 32 KB double-buffered quarter slab
    __shared__ float lgt[ROWS * 64];        // 16 KB logits [row][gate]
    __shared__ float wT[64 * ROWS];         // 16 KB softmax weights [gate][row]

    const int tid  = threadIdx.x;
    const int wv   = tid >> 6;        // wave id 0..7
    const int lane = tid & 63;
    const int rg   = wv >> 2;         // row-group 0..1
    const int cg   = wv & 3;          // col-group 0..3
    const int quad = lane >> 4;
    const int l16  = lane & 15;
    const int r0   = blockIdx.x * ROWS;
    const int rb   = r0 + rg * 32;    // this wave's row base
    const int rot  = (blockIdx.x >> 3) & 7;

    // Prologue: stage interval 0 into slot 0; completes under phase 1's
    // __syncthreads (vmcnt drained at barrier).
    stage_q(wp, ring, qslab_of(0, rot), 0, wv, lane);

    bfv8 afr[2][8];                   // A frags: 2 row-tiles x 8 k-tiles (64 VGPRs)

    // ---------------- Phase 1: gate logits via MFMA (R7) ----------------
    {
        const float* x = (cg == 0) ? xa : (cg == 1) ? xb : xs;  // wave-uniform
        load_afr(x, rb, l16, quad, afr);
        f32x4 acc1[2];
#pragma unroll
        for (int mt = 0; mt < 2; mt++) { f32x4 z = {0.f, 0.f, 0.f, 0.f}; acc1[mt] = z; }
#pragma unroll
        for (int kt = 0; kt < 8; kt++) {
            bfv8 gfr = *(const bfv8*)(gp + ((size_t)(kt * 4 + cg) * 64 + lane) * 8);
#pragma unroll
            for (int mt = 0; mt < 2; mt++)
                acc1[mt] = __builtin_amdgcn_mfma_f32_16x16x32_bf16(afr[mt][kt], gfr, acc1[mt], 0, 0, 0);
        }
#pragma unroll
        for (int mt = 0; mt < 2; mt++)
#pragma unroll
            for (int r = 0; r < 4; r++)
                lgt[(rg * 32 + mt * 16 + quad * 4 + r) * 64 + cg * 16 + l16] = acc1[mt][r];
    }
    __syncthreads();

    // ---------------- softmax per row (64 rows, one wave) (R7) ----------------
    if (tid < ROWS) {
        const float* L = lgt + tid * 64;
#pragma unroll
        for (int gi = 0; gi < 3; gi++) {
            const int base = (gi == 0) ? 0 : (gi == 1 ? 16 : 32);
            const int cnt  = (gi == 2) ? 24 : 16;
            float m = -1e30f;
            for (int k = 0; k < cnt; k++) m = fmaxf(m, L[base + k]);
            float s = 0.f;
            for (int k = 0; k < cnt; k++) s += __expf(L[base + k] - m);
            float inv = 1.f / s;
            for (int k = 0; k < cnt; k++) wT[(base + k) * ROWS + tid] = __expf(L[base + k] - m) * inv;
        }
    }
    __syncthreads();

    // ---------------- Phase 2: experts + gated accumulation (R7) --------------
    float o[3][2][2][4];
#pragma unroll
    for (int oi = 0; oi < 3; oi++)
#pragma unroll
        for (int mt = 0; mt < 2; mt++)
#pragma unroll
            for (int ntl = 0; ntl < 2; ntl++)
#pragma unroll
                for (int r = 0; r < 4; r++) o[oi][mt][ntl][r] = 0.f;

#define FOLD(oi, gbase)                                                                 \
    {                                                                                   \
        _Pragma("unroll")                                                               \
        for (int mt = 0; mt < 2; mt++) {                                                \
            f32x4 gw4 = *(const f32x4*)(wT + (gbase + eb) * ROWS + rg * 32 + mt * 16 + quad * 4); \
            _Pragma("unroll")                                                           \
            for (int ntl = 0; ntl < 2; ntl++)                                           \
                _Pragma("unroll")                                                       \
                for (int r = 0; r < 4; r++)                                             \
                    o[oi][mt][ntl][r] += gw4[r] * acc[mt][ntl][r];                      \
        }                                                                               \
    }

#pragma unroll
    for (int st = 0; st < 3; st++) {
        const float* x    = (st == 0) ? xa : (st == 1) ? xb : xs;
        const float* bias = (st == 0) ? ba : (st == 1) ? bb : bs;
        load_afr(x, rb, l16, quad, afr);

#pragma unroll 1
        for (int eb0 = 0; eb0 < NEXP; eb0++) {
            const int eb = (eb0 + rot) & 7;
            float b0 = bias[eb * 128 + cg * 32 + l16];
            float b1 = bias[eb * 128 + cg * 32 + 16 + l16];

            f32x4 acc[2][2];
#pragma unroll
            for (int mt = 0; mt < 2; mt++)
#pragma unroll
                for (int ntl = 0; ntl < 2; ntl++) { f32x4 z = {0.f, 0.f, 0.f, 0.f}; acc[mt][ntl] = z; }

            // acc accumulates over 4 quarter-expert intervals (kt 0..7)
#pragma unroll
            for (int q = 0; q < 4; q++) {
                const int s = st * 32 + eb0 * 4 + q;     // interval 0..95
                __syncthreads();                         // drains stage(s)
                if (s + 1 < NSEQ)
                    stage_q(wp, ring, qslab_of(s + 1, rot), (s + 1) & 1, wv, lane);

                const __bf16* buf = ring + ((s & 1) << 13);
#pragma unroll
                for (int j = 0; j < 2; j++) {
                    const int kt = q * 2 + j;
                    const __bf16* slab = buf + (j << 12) + (cg << 10);
                    bfv8 bv0 = *(const bfv8*)(slab + ((size_t)lane << 3));
                    bfv8 bv1 = *(const bfv8*)(slab + 512 + ((size_t)lane << 3));
                    acc[0][0] = __builtin_amdgcn_mfma_f32_16x16x32_bf16(afr[0][kt], bv0, acc[0][0], 0, 0, 0);
                    acc[1][0] = __builtin_amdgcn_mfma_f32_16x16x32_bf16(afr[1][kt], bv0, acc[1][0], 0, 0, 0);
                    acc[0][1] = __builtin_amdgcn_mfma_f32_16x16x32_bf16(afr[0][kt], bv1, acc[0][1], 0, 0, 0);
                    acc[1][1] = __builtin_amdgcn_mfma_f32_16x16x32_bf16(afr[1][kt], bv1, acc[1][1], 0, 0, 0);
                }
            }

            // bias (per output column)
#pragma unroll
            for (int mt = 0; mt < 2; mt++)
#pragma unroll
                for (int r = 0; r < 4; r++) { acc[mt][0][r] += b0; acc[mt][1][r] += b1; }

            // gated fold. Gate table columns: a:0-15, b:16-31, s:32-55.
            if (st == 0)      { FOLD(0, 0);  FOLD(2, 32); }
            else if (st == 1) { FOLD(1, 16); FOLD(2, 40); }
            else              { FOLD(0, 8);  FOLD(1, 24); FOLD(2, 48); }
        }
    }
#undef FOLD

    // ---------------- epilogue: store 3 outputs (nontemporal) (R7) ------------
#pragma unroll
    for (int oi = 0; oi < 3; oi++) {
        float* ob = out + (size_t)oi * BATCH * DDIM;
#pragma unroll
        for (int mt = 0; mt < 2; mt++)
#pragma unroll
            for (int r = 0; r < 4; r++) {
                int row = rb + mt * 16 + quad * 4 + r;
#pragma unroll
                for (int ntl = 0; ntl < 2; ntl++)
                    __builtin_nontemporal_store(o[oi][mt][ntl][r],
                        &ob[(size_t)row * DDIM + cg * 32 + ntl * 16 + l16]);
            }
    }
}

extern "C" void kernel_launch(void* const* d_in, const int* in_sizes, int n_in,
                              void* d_out, int out_size, void* d_ws, size_t ws_size,
                              hipStream_t stream) {
    const float* xa = (const float*)d_in[0];
    const float* xb = (const float*)d_in[1];
    const float* xs = (const float*)d_in[2];
    const float* Wa = (const float*)d_in[3];
    const float* ba = (const float*)d_in[4];
    const float* Wb = (const float*)d_in[5];
    const float* bb = (const float*)d_in[6];
    const float* Ws = (const float*)d_in[7];
    const float* bs = (const float*)d_in[8];
    const float* Ga = (const float*)d_in[9];
    const float* Gb = (const float*)d_in[10];
    const float* Gs = (const float*)d_in[11];

    __bf16* wp = (__bf16*)d_ws;                 // 1.5 MB packed expert weights
    __bf16* gp = wp + 3 * 8 * 8 * 8 * 64 * 8;   // 32 KB packed gate matrix

    prep_kernel<<<200, 256, 0, stream>>>(Wa, Wb, Ws, Ga, Gb, Gs, wp, gp);
    ple_kernel<<<BATCH / ROWS, THREADS, 0, stream>>>(xa, xb, xs, ba, bb, bs, wp, gp, (float*)d_out);
}

// Round 15
// 203.748 us; speedup vs baseline: 1.0684x; 1.0679x over previous
//
#include <hip/hip_runtime.h>
#include <stdint.h>

// Problem constants
#define BATCH 16384
#define INDIM 256
#define DDIM  128
#define NEXP  8
#define ROWS  64          // batch rows per block
#define THREADS 512       // 8 waves
#define NSEQ  48          // staging intervals: (st, eb0, half) half-expert slabs
#define HSLAB 8192        // bf16 elems staged per interval (block's 64-col half)

typedef __bf16 bfv8  __attribute__((ext_vector_type(8)));   // MFMA A/B frag: 8 bf16 = 4 VGPRs
typedef float  f32x4 __attribute__((ext_vector_type(4)));   // MFMA C/D frag

typedef __attribute__((address_space(1))) const void gas_void;
typedef __attribute__((address_space(3))) void las_void;

// ---------------------------------------------------------------------------
// Prep kernel (R7 version, unchanged, passing): coalesced repack of Wa/Wb/Ws
// and gate matrices into bf16 MFMA B-fragment layout. Contract:
//   wp + g*4096 + nt*512 + lane*8 + j = (bf16) W_st[e*256 + kt*32 +
//     (lane>>4)*8 + j][nt*16 + (lane&15)],  g = st*64 + e*8 + kt.
// ---------------------------------------------------------------------------
__global__ void prep_kernel(const float* __restrict__ Wa, const float* __restrict__ Wb,
                            const float* __restrict__ Ws, const float* __restrict__ Ga,
                            const float* __restrict__ Gb, const float* __restrict__ Gs,
                            __bf16* __restrict__ wp, __bf16* __restrict__ gp) {
    __shared__ float ws[32 * 132];          // 32 rows x 128 cols, pad 4
    const int b = blockIdx.x, tid = threadIdx.x;
    if (b < 192) {
        const int st = b >> 6, e = (b >> 3) & 7, kt = b & 7;
        const float* W = (st == 0) ? Wa : (st == 1) ? Wb : Ws;
        const float* src = W + (size_t)(e * 256 + kt * 32) * 128;
#pragma unroll
        for (int k = 0; k < 4; k++) {
            int idx4 = tid + k * 256;
            f32x4 v = *(const f32x4*)(src + (size_t)idx4 * 4);
            int row = idx4 >> 5;
            int col = (idx4 & 31) << 2;
            ws[row * 132 + col + 0] = v[0];
            ws[row * 132 + col + 1] = v[1];
            ws[row * 132 + col + 2] = v[2];
            ws[row * 132 + col + 3] = v[3];
        }
        __syncthreads();
        __bf16* o = wp + ((size_t)b << 12);
#pragma unroll
        for (int h2 = 0; h2 < 2; h2++) {
            int base = tid * 2 + h2;
            int nt = base >> 6, lane = base & 63;
            int d  = nt * 16 + (lane & 15);
            int i0 = (lane >> 4) * 8;
            bfv8 ov;
#pragma unroll
            for (int j = 0; j < 8; j++) ov[j] = (__bf16)ws[(i0 + j) * 132 + d];
            *(bfv8*)(o + (size_t)base * 8) = ov;
        }
    } else {
        int t2 = (b - 192) * 256 + tid;
        int lane = t2 & 63, nt = (t2 >> 6) & 3, kt = t2 >> 8;
        int g  = nt * 16 + (lane & 15);
        int k0 = kt * 32 + (lane >> 4) * 8;
        __bf16* o = gp + (size_t)t2 * 8;
#pragma unroll
        for (int j = 0; j < 8; j++) {
            int k = k0 + j;
            float v = 0.f;
            if (g < 16)      v = Ga[g * 256 + k];
            else if (g < 32) v = Gb[(g - 16) * 256 + k];
            else if (g < 56) v = Gs[(g - 32) * 256 + k];
            o[j] = (__bf16)v;
        }
    }
}

// Phase-1 A fragments (2 row-tiles x 8 k-tiles), fp32->bf16, nontemporal (R7).
__device__ __forceinline__ void load_afr(const float* __restrict__ x, int rb,
                                         int l16, int quad, bfv8 afr[2][8]) {
#pragma unroll
    for (int mt = 0; mt < 2; mt++) {
        const float* xr = x + (size_t)(rb + mt * 16 + l16) * INDIM;
#pragma unroll
        for (int kt = 0; kt < 8; kt++) {
            const f32x4* p = (const f32x4*)(xr + kt * 32 + quad * 8);
            f32x4 lo = __builtin_nontemporal_load(p);
            f32x4 hi = __builtin_nontemporal_load(p + 1);
            bfv8 a;
            a[0] = (__bf16)lo[0]; a[1] = (__bf16)lo[1]; a[2] = (__bf16)lo[2]; a[3] = (__bf16)lo[3];
            a[4] = (__bf16)hi[0]; a[5] = (__bf16)hi[1]; a[6] = (__bf16)hi[2]; a[7] = (__bf16)hi[3];
            afr[mt][kt] = a;
        }
    }
}

// Phase-2 A fragments (ONE 16-row tile x 8 k-tiles). Same per-lane layout.
__device__ __forceinline__ void load_afr16(const float* __restrict__ x, int rbase,
                                           int l16, int quad, bfv8 afr[8]) {
    const float* xr = x + (size_t)(rbase + l16) * INDIM;
#pragma unroll
    for (int kt = 0; kt < 8; kt++) {
        const f32x4* p = (const f32x4*)(xr + kt * 32 + quad * 8);
        f32x4 lo = __builtin_nontemporal_load(p);
        f32x4 hi = __builtin_nontemporal_load(p + 1);
        bfv8 a;
        a[0] = (__bf16)lo[0]; a[1] = (__bf16)lo[1]; a[2] = (__bf16)lo[2]; a[3] = (__bf16)lo[3];
        a[4] = (__bf16)hi[0]; a[5] = (__bf16)hi[1]; a[6] = (__bf16)hi[2]; a[7] = (__bf16)hi[3];
        afr[kt] = a;
    }
}

// Stage one interval: the block's 64-col half of a half-expert slab (16 KB =
// 4 kt-slabs x 2048 elems). 8 waves x 2 glls of 1KB. Wave wv covers interval
// elems [wv*1024, +1024): kt4 = wv>>1, col-region offset (wv&1)*1024.
// LDS dest wave-uniform + lane*16B (HW rule); linear layout [kt4][2048].
__device__ __forceinline__ void stage_h(const __bf16* __restrict__ wp,
                                        __bf16* ring, int hs, int slot,
                                        int co, int wv, int lane) {
    const __bf16* src = wp + ((size_t)(hs * 4 + (wv >> 1)) << 12)
                           + (co << 11) + ((wv & 1) << 10) + (lane << 3);
    __bf16* dst = ring + (slot << 13) + ((size_t)wv << 10);
#pragma unroll
    for (int i = 0; i < 2; i++)
        __builtin_amdgcn_global_load_lds((gas_void*)(src + (i << 9)),
                                         (las_void*)(dst + (i << 9)), 16, 0, 0);
}

// Rotation (R7, +4-5% proven): interval s = st*16 + eb0*2 + half -> physical
// half-slab index st*16 + eb*2 + half with eb = (eb0+rot)&7.
__device__ __forceinline__ int hs_of(int s, int rot) {
    int st = s >> 4;
    int eb = (((s >> 1) & 7) + rot) & 7;
    return (st << 4) | (eb << 1) | (s & 1);
}

// ---------------------------------------------------------------------------
// Main fused kernel R11: FINALLY run the 16-waves/CU experiment correctly.
// R10 post-mortem: grid=256 can never give 2 blocks/CU (occupancy stuck at
// 8 waves/CU in EVERY round R4-R10), and launch_bounds(,4) forced VGPR 64 ->
// spills (WRITE_SIZE 25->51MB). Fix both:
//   grid 512: bid -> (rblk = bid>>1, co = bid&1); block = 64 rows x 64 cols
//   (col-split keeps weight traffic at 512 x 0.75MB = 384MB, unlike R8's
//   row-split), ring stages only the block's col-half (8KB/interval, dbuf
//   16KB) -> LDS 64KB total -> 2 blocks/CU; launch_bounds(512,2) (R7-proven
//   VGPR 96, no spill; 96 VGPR => 16 waves/CU per m69).
// Phase 1 + softmax byte-identical to passing R7/R10 (waves 2rg x 4cg over
// all 64 gates). Phase 2 waves remapped: rg2 = wv>>1 (16-row tile),
// cgl = wv&1 (32-col tile at co*64 + cgl*32). NSEQ=48 cadence (R7-proven).
// ---------------------------------------------------------------------------
__launch_bounds__(THREADS, 2)
__global__ void ple_kernel(const float* __restrict__ xa, const float* __restrict__ xb,
                           const float* __restrict__ xs,
                           const float* __restrict__ ba, const float* __restrict__ bb,
                           const float* __restrict__ bs,
                           const __bf16* __restrict__ wp, const __bf16* __restrict__ gp,
                           float* __restrict__ out) {
    __shared__ __bf16 ring[2 * HSLAB];      // 32 KB double-buffered col-half slab
    __shared__ float lgt[ROWS * 64];        // 16 KB logits [row][gate]
    __shared__ float wT[64 * ROWS];         // 16 KB softmax weights [gate][row]

    const int tid  = threadIdx.x;
    const int wv   = tid >> 6;        // wave id 0..7
    const int lane = tid & 63;
    const int quad = lane >> 4;
    const int l16  = lane & 15;
    const int bid  = blockIdx.x;
    const int r0   = (bid >> 1) * ROWS;   // row block
    const int co   = bid & 1;             // column half 0..1 (cols co*64..+64)
    const int rot  = (bid >> 3) & 7;

    // Prologue: stage interval 0 into slot 0; completes under phase 1's
    // __syncthreads (vmcnt drained at barrier).
    stage_h(wp, ring, hs_of(0, rot), 0, co, wv, lane);

    // ---------------- Phase 1: gate logits via MFMA (R7, unchanged) ---------
    {
        const int rg = wv >> 2;           // 0..1 (32-row groups)
        const int cg = wv & 3;            // 0..3 (16-gate groups)
        const int rb = r0 + rg * 32;
        bfv8 afr[2][8];
        const float* x = (cg == 0) ? xa : (cg == 1) ? xb : xs;  // wave-uniform
        load_afr(x, rb, l16, quad, afr);
        f32x4 acc1[2];
#pragma unroll
        for (int mt = 0; mt < 2; mt++) { f32x4 z = {0.f, 0.f, 0.f, 0.f}; acc1[mt] = z; }
#pragma unroll
        for (int kt = 0; kt < 8; kt++) {
            bfv8 gfr = *(const bfv8*)(gp + ((size_t)(kt * 4 + cg) * 64 + lane) * 8);
#pragma unroll
            for (int mt = 0; mt < 2; mt++)
                acc1[mt] = __builtin_amdgcn_mfma_f32_16x16x32_bf16(afr[mt][kt], gfr, acc1[mt], 0, 0, 0);
        }
#pragma unroll
        for (int mt = 0; mt < 2; mt++)
#pragma unroll
            for (int r = 0; r < 4; r++)
                lgt[(rg * 32 + mt * 16 + quad * 4 + r) * 64 + cg * 16 + l16] = acc1[mt][r];
    }
    __syncthreads();

    // ---------------- softmax per row (64 rows, one wave) (R7) ----------------
    if (tid < ROWS) {
        const float* L = lgt + tid * 64;
#pragma unroll
        for (int gi = 0; gi < 3; gi++) {
            const int base = (gi == 0) ? 0 : (gi == 1 ? 16 : 32);
            const int cnt  = (gi == 2) ? 24 : 16;
            float m = -1e30f;
            for (int k = 0; k < cnt; k++) m = fmaxf(m, L[base + k]);
            float s = 0.f;
            for (int k = 0; k < cnt; k++) s += __expf(L[base + k] - m);
            float inv = 1.f / s;
            for (int k = 0; k < cnt; k++) wT[(base + k) * ROWS + tid] = __expf(L[base + k] - m) * inv;
        }
    }
    __syncthreads();

    // ---------------- Phase 2: experts, waves remapped 4rg x 2cgl ------------
    const int rg2   = wv >> 1;        // 0..3: 16-row tile
    const int cgl   = wv & 1;         // 0..1: 32-col tile within block's half
    const int rbase = r0 + rg2 * 16;

    bfv8 afr2[8];
    float o[3][2][4];                 // [out][ntl][reg]
#pragma unroll
    for (int oi = 0; oi < 3; oi++)
#pragma unroll
        for (int ntl = 0; ntl < 2; ntl++)
#pragma unroll
            for (int r = 0; r < 4; r++) o[oi][ntl][r] = 0.f;

#define FOLD(oi, gbase)                                                              \
    {                                                                                \
        f32x4 gw4 = *(const f32x4*)(wT + (gbase + eb) * ROWS + rg2 * 16 + quad * 4); \
        _Pragma("unroll")                                                            \
        for (int ntl = 0; ntl < 2; ntl++)                                            \
            _Pragma("unroll")                                                        \
            for (int r = 0; r < 4; r++)                                              \
                o[oi][ntl][r] += gw4[r] * acc[ntl][r];                               \
    }

#pragma unroll
    for (int st = 0; st < 3; st++) {
        const float* x    = (st == 0) ? xa : (st == 1) ? xb : xs;
        const float* bias = (st == 0) ? ba : (st == 1) ? bb : bs;
        load_afr16(x, rbase, l16, quad, afr2);

#pragma unroll 1
        for (int eb0 = 0; eb0 < NEXP; eb0++) {
            const int eb = (eb0 + rot) & 7;
            float b0 = bias[eb * 128 + co * 64 + cgl * 32 + l16];
            float b1 = bias[eb * 128 + co * 64 + cgl * 32 + 16 + l16];

            f32x4 acc[2];
#pragma unroll
            for (int ntl = 0; ntl < 2; ntl++) { f32x4 z = {0.f, 0.f, 0.f, 0.f}; acc[ntl] = z; }

            // acc accumulates over both half-expert intervals (kt 0..7)
#pragma unroll
            for (int half = 0; half < 2; half++) {
                const int s = st * 16 + eb0 * 2 + half;  // interval 0..47
                __syncthreads();                         // drains stage(s)
                if (s + 1 < NSEQ)
                    stage_h(wp, ring, hs_of(s + 1, rot), (s + 1) & 1, co, wv, lane);

                const __bf16* buf = ring + ((s & 1) << 13);
#pragma unroll
                for (int kt4 = 0; kt4 < 4; kt4++) {
                    const int kt = half * 4 + kt4;
                    const __bf16* reg = buf + (kt4 << 11) + (cgl << 10);
                    bfv8 bv0 = *(const bfv8*)(reg + ((size_t)lane << 3));
                    bfv8 bv1 = *(const bfv8*)(reg + 512 + ((size_t)lane << 3));
                    acc[0] = __builtin_amdgcn_mfma_f32_16x16x32_bf16(afr2[kt], bv0, acc[0], 0, 0, 0);
                    acc[1] = __builtin_amdgcn_mfma_f32_16x16x32_bf16(afr2[kt], bv1, acc[1], 0, 0, 0);
                }
            }

            // bias (per output column)
#pragma unroll
            for (int r = 0; r < 4; r++) { acc[0][r] += b0; acc[1][r] += b1; }

            // gated fold. Gate table columns: a:0-15, b:16-31, s:32-55.
            if (st == 0)      { FOLD(0, 0);  FOLD(2, 32); }
            else if (st == 1) { FOLD(1, 16); FOLD(2, 40); }
            else              { FOLD(0, 8);  FOLD(1, 24); FOLD(2, 48); }
        }
    }
#undef FOLD

    // ---------------- epilogue: store 3 outputs (nontemporal) ----------------
#pragma unroll
    for (int oi = 0; oi < 3; oi++) {
        float* ob = out + (size_t)oi * BATCH * DDIM;
#pragma unroll
        for (int r = 0; r < 4; r++) {
            int row = rbase + quad * 4 + r;
#pragma unroll
            for (int ntl = 0; ntl < 2; ntl++)
                __builtin_nontemporal_store(o[oi][ntl][r],
                    &ob[(size_t)row * DDIM + co * 64 + cgl * 32 + ntl * 16 + l16]);
        }
    }
}

extern "C" void kernel_launch(void* const* d_in, const int* in_sizes, int n_in,
                              void* d_out, int out_size, void* d_ws, size_t ws_size,
                              hipStream_t stream) {
    const float* xa = (const float*)d_in[0];
    const float* xb = (const float*)d_in[1];
    const float* xs = (const float*)d_in[2];
    const float* Wa = (const float*)d_in[3];
    const float* ba = (const float*)d_in[4];
    const float* Wb = (const float*)d_in[5];
    const float* bb = (const float*)d_in[6];
    const float* Ws = (const float*)d_in[7];
    const float* bs = (const float*)d_in[8];
    const float* Ga = (const float*)d_in[9];
    const float* Gb = (const float*)d_in[10];
    const float* Gs = (const float*)d_in[11];

    __bf16* wp = (__bf16*)d_ws;                 // 1.5 MB packed expert weights
    __bf16* gp = wp + 3 * 8 * 8 * 8 * 64 * 8;   // 32 KB packed gate matrix

    prep_kernel<<<200, 256, 0, stream>>>(Wa, Wb, Ws, Ga, Gb, Gs, wp, gp);
    ple_kernel<<<2 * (BATCH / ROWS), THREADS, 0, stream>>>(xa, xb, xs, ba, bb, bs, wp, gp, (float*)d_out);
}

// Round 17
// 195.773 us; speedup vs baseline: 1.1120x; 1.0407x over previous
//
#include <hip/hip_runtime.h>
#include <stdint.h>

// Problem constants
#define BATCH 16384
#define INDIM 256
#define DDIM  128
#define NEXP  8
#define ROWS  64          // batch rows per block
#define THREADS 512       // 8 waves
#define NSEQ  96          // staging intervals: (st, eb0, q) kt-pair x col-half
#define QSLB  4096        // bf16 elems staged per interval (8 KB)

typedef __bf16 bfv8  __attribute__((ext_vector_type(8)));   // MFMA A/B frag: 8 bf16 = 4 VGPRs
typedef float  f32x4 __attribute__((ext_vector_type(4)));   // MFMA C/D frag

typedef __attribute__((address_space(1))) const void gas_void;
typedef __attribute__((address_space(3))) void las_void;

// ---------------------------------------------------------------------------
// Prep kernel (R7 version, unchanged, passing): coalesced repack of Wa/Wb/Ws
// and gate matrices into bf16 MFMA B-fragment layout. Contract:
//   wp + g*4096 + nt*512 + lane*8 + j = (bf16) W_st[e*256 + kt*32 +
//     (lane>>4)*8 + j][nt*16 + (lane&15)],  g = st*64 + e*8 + kt.
// ---------------------------------------------------------------------------
__global__ void prep_kernel(const float* __restrict__ Wa, const float* __restrict__ Wb,
                            const float* __restrict__ Ws, const float* __restrict__ Ga,
                            const float* __restrict__ Gb, const float* __restrict__ Gs,
                            __bf16* __restrict__ wp, __bf16* __restrict__ gp) {
    __shared__ float ws[32 * 132];          // 32 rows x 128 cols, pad 4
    const int b = blockIdx.x, tid = threadIdx.x;
    if (b < 192) {
        const int st = b >> 6, e = (b >> 3) & 7, kt = b & 7;
        const float* W = (st == 0) ? Wa : (st == 1) ? Wb : Ws;
        const float* src = W + (size_t)(e * 256 + kt * 32) * 128;
#pragma unroll
        for (int k = 0; k < 4; k++) {
            int idx4 = tid + k * 256;
            f32x4 v = *(const f32x4*)(src + (size_t)idx4 * 4);
            int row = idx4 >> 5;
            int col = (idx4 & 31) << 2;
            ws[row * 132 + col + 0] = v[0];
            ws[row * 132 + col + 1] = v[1];
            ws[row * 132 + col + 2] = v[2];
            ws[row * 132 + col + 3] = v[3];
        }
        __syncthreads();
        __bf16* o = wp + ((size_t)b << 12);
#pragma unroll
        for (int h2 = 0; h2 < 2; h2++) {
            int base = tid * 2 + h2;
            int nt = base >> 6, lane = base & 63;
            int d  = nt * 16 + (lane & 15);
            int i0 = (lane >> 4) * 8;
            bfv8 ov;
#pragma unroll
            for (int j = 0; j < 8; j++) ov[j] = (__bf16)ws[(i0 + j) * 132 + d];
            *(bfv8*)(o + (size_t)base * 8) = ov;
        }
    } else {
        int t2 = (b - 192) * 256 + tid;
        int lane = t2 & 63, nt = (t2 >> 6) & 3, kt = t2 >> 8;
        int g  = nt * 16 + (lane & 15);
        int k0 = kt * 32 + (lane >> 4) * 8;
        __bf16* o = gp + (size_t)t2 * 8;
#pragma unroll
        for (int j = 0; j < 8; j++) {
            int k = k0 + j;
            float v = 0.f;
            if (g < 16)      v = Ga[g * 256 + k];
            else if (g < 32) v = Gb[(g - 16) * 256 + k];
            else if (g < 56) v = Gs[(g - 32) * 256 + k];
            o[j] = (__bf16)v;
        }
    }
}

// Phase-1 A fragments (2 row-tiles x 8 k-tiles), fp32->bf16, nontemporal (R7).
__device__ __forceinline__ void load_afr(const float* __restrict__ x, int rb,
                                         int l16, int quad, bfv8 afr[2][8]) {
#pragma unroll
    for (int mt = 0; mt < 2; mt++) {
        const float* xr = x + (size_t)(rb + mt * 16 + l16) * INDIM;
#pragma unroll
        for (int kt = 0; kt < 8; kt++) {
            const f32x4* p = (const f32x4*)(xr + kt * 32 + quad * 8);
            f32x4 lo = __builtin_nontemporal_load(p);
            f32x4 hi = __builtin_nontemporal_load(p + 1);
            bfv8 a;
            a[0] = (__bf16)lo[0]; a[1] = (__bf16)lo[1]; a[2] = (__bf16)lo[2]; a[3] = (__bf16)lo[3];
            a[4] = (__bf16)hi[0]; a[5] = (__bf16)hi[1]; a[6] = (__bf16)hi[2]; a[7] = (__bf16)hi[3];
            afr[mt][kt] = a;
        }
    }
}

// Phase-2 A fragments (ONE 16-row tile x 8 k-tiles). Same per-lane layout.
__device__ __forceinline__ void load_afr16(const float* __restrict__ x, int rbase,
                                           int l16, int quad, bfv8 afr[8]) {
    const float* xr = x + (size_t)(rbase + l16) * INDIM;
#pragma unroll
    for (int kt = 0; kt < 8; kt++) {
        const f32x4* p = (const f32x4*)(xr + kt * 32 + quad * 8);
        f32x4 lo = __builtin_nontemporal_load(p);
        f32x4 hi = __builtin_nontemporal_load(p + 1);
        bfv8 a;
        a[0] = (__bf16)lo[0]; a[1] = (__bf16)lo[1]; a[2] = (__bf16)lo[2]; a[3] = (__bf16)lo[3];
        a[4] = (__bf16)hi[0]; a[5] = (__bf16)hi[1]; a[6] = (__bf16)hi[2]; a[7] = (__bf16)hi[3];
        afr[kt] = a;
    }
}

// Stage one interval: kt-pair x block's 64-col half = 4096 elems (8 KB).
// 8 waves x 1 gll of 1KB. Wave wv covers elems [wv*512, +512):
//   kt-sub j = wv>>2, within-kt 512-region r = wv&3 (2048 elems per kt-slab
//   col-half; j*2048 + r*512 == wv*512). LDS dest wave-uniform + lane*16B.
// ks = base kt-slab index (physical), co = column half.
__device__ __forceinline__ void stage_kt2(const __bf16* __restrict__ wp,
                                          __bf16* ring, int ks, int slot,
                                          int co, int wv, int lane) {
    const __bf16* src = wp + ((size_t)(ks + (wv >> 2)) << 12)
                           + (co << 11) + ((wv & 3) << 9) + (lane << 3);
    __bf16* dst = ring + (slot << 12) + ((size_t)wv << 9);
    __builtin_amdgcn_global_load_lds((gas_void*)src, (las_void*)dst, 16, 0, 0);
}

// Rotation (R7, +4-5% proven): interval s = st*32 + eb0*4 + q -> physical
// base kt-slab st*64 + eb*8 + q*2, eb = (eb0+rot)&7.
__device__ __forceinline__ int ks_of(int s, int rot) {
    int st = s >> 5;
    int eb = (((s >> 2) & 7) + rot) & 7;
    return st * 64 + eb * 8 + (s & 3) * 2;
}

// ---------------------------------------------------------------------------
// Main fused kernel R12 = R11 (passing) with LDS cut 64KB -> 48KB to fit 2
// blocks under the LDS pool boundary. Occupancy forensics (R8 vs R11 +
// m132): usable pool is in [80,128) KB -- R11's 2x64KB just missed, so every
// round R4-R11 ran 8 waves/CU and the TLP experiment never executed. R12:
// ring stages 8KB/interval (kt-pair x col-half, NSEQ 96, 1 gll/wave) ->
// ring 16KB + lgt 16KB + wT 16KB = 48KB -> 2 blocks/CU (96KB <= pool) at
// grid 512 -> 16 waves/CU. Two INDEPENDENT blocks overlap each other's
// barrier drains (m114/m97 mechanism: 874 TF at 3 blocks/CU with the same
// 2-barrier structure). All else identical to R11 (passed, 115us).
// ---------------------------------------------------------------------------
__launch_bounds__(THREADS, 2)
__global__ void ple_kernel(const float* __restrict__ xa, const float* __restrict__ xb,
                           const float* __restrict__ xs,
                           const float* __restrict__ ba, const float* __restrict__ bb,
                           const float* __restrict__ bs,
                           const __bf16* __restrict__ wp, const __bf16* __restrict__ gp,
                           float* __restrict__ out) {
    __shared__ __bf16 ring[2 * QSLB];       // 16 KB double-buffered interval
    __shared__ float lgt[ROWS * 64];        // 16 KB logits [row][gate]
    __shared__ float wT[64 * ROWS];         // 16 KB softmax weights [gate][row]

    const int tid  = threadIdx.x;
    const int wv   = tid >> 6;        // wave id 0..7
    const int lane = tid & 63;
    const int quad = lane >> 4;
    const int l16  = lane & 15;
    const int bid  = blockIdx.x;
    const int r0   = (bid >> 1) * ROWS;   // row block
    const int co   = bid & 1;             // column half 0..1 (cols co*64..+64)
    const int rot  = (bid >> 3) & 7;

    // Prologue: stage interval 0 into slot 0; completes under phase 1's
    // __syncthreads (vmcnt drained at barrier).
    stage_kt2(wp, ring, ks_of(0, rot), 0, co, wv, lane);

    // ---------------- Phase 1: gate logits via MFMA (R11, unchanged) --------
    {
        const int rg = wv >> 2;           // 0..1 (32-row groups)
        const int cg = wv & 3;            // 0..3 (16-gate groups)
        const int rb = r0 + rg * 32;
        bfv8 afr[2][8];
        const float* x = (cg == 0) ? xa : (cg == 1) ? xb : xs;  // wave-uniform
        load_afr(x, rb, l16, quad, afr);
        f32x4 acc1[2];
#pragma unroll
        for (int mt = 0; mt < 2; mt++) { f32x4 z = {0.f, 0.f, 0.f, 0.f}; acc1[mt] = z; }
#pragma unroll
        for (int kt = 0; kt < 8; kt++) {
            bfv8 gfr = *(const bfv8*)(gp + ((size_t)(kt * 4 + cg) * 64 + lane) * 8);
#pragma unroll
            for (int mt = 0; mt < 2; mt++)
                acc1[mt] = __builtin_amdgcn_mfma_f32_16x16x32_bf16(afr[mt][kt], gfr, acc1[mt], 0, 0, 0);
        }
#pragma unroll
        for (int mt = 0; mt < 2; mt++)
#pragma unroll
            for (int r = 0; r < 4; r++)
                lgt[(rg * 32 + mt * 16 + quad * 4 + r) * 64 + cg * 16 + l16] = acc1[mt][r];
    }
    __syncthreads();

    // ---------------- softmax per row (64 rows, one wave) (R11) ---------------
    if (tid < ROWS) {
        const float* L = lgt + tid * 64;
#pragma unroll
        for (int gi = 0; gi < 3; gi++) {
            const int base = (gi == 0) ? 0 : (gi == 1 ? 16 : 32);
            const int cnt  = (gi == 2) ? 24 : 16;
            float m = -1e30f;
            for (int k = 0; k < cnt; k++) m = fmaxf(m, L[base + k]);
            float s = 0.f;
            for (int k = 0; k < cnt; k++) s += __expf(L[base + k] - m);
            float inv = 1.f / s;
            for (int k = 0; k < cnt; k++) wT[(base + k) * ROWS + tid] = __expf(L[base + k] - m) * inv;
        }
    }
    __syncthreads();

    // ---------------- Phase 2: experts, waves 4rg x 2cgl (R11) ---------------
    const int rg2   = wv >> 1;        // 0..3: 16-row tile
    const int cgl   = wv & 1;         // 0..1: 32-col tile within block's half
    const int rbase = r0 + rg2 * 16;

    bfv8 afr2[8];
    float o[3][2][4];                 // [out][ntl][reg]
#pragma unroll
    for (int oi = 0; oi < 3; oi++)
#pragma unroll
        for (int ntl = 0; ntl < 2; ntl++)
#pragma unroll
            for (int r = 0; r < 4; r++) o[oi][ntl][r] = 0.f;

#define FOLD(oi, gbase)                                                              \
    {                                                                                \
        f32x4 gw4 = *(const f32x4*)(wT + (gbase + eb) * ROWS + rg2 * 16 + quad * 4); \
        _Pragma("unroll")                                                            \
        for (int ntl = 0; ntl < 2; ntl++)                                            \
            _Pragma("unroll")                                                        \
            for (int r = 0; r < 4; r++)                                              \
                o[oi][ntl][r] += gw4[r] * acc[ntl][r];                               \
    }

#pragma unroll
    for (int st = 0; st < 3; st++) {
        const float* x    = (st == 0) ? xa : (st == 1) ? xb : xs;
        const float* bias = (st == 0) ? ba : (st == 1) ? bb : bs;
        load_afr16(x, rbase, l16, quad, afr2);

#pragma unroll 1
        for (int eb0 = 0; eb0 < NEXP; eb0++) {
            const int eb = (eb0 + rot) & 7;
            float b0 = bias[eb * 128 + co * 64 + cgl * 32 + l16];
            float b1 = bias[eb * 128 + co * 64 + cgl * 32 + 16 + l16];

            f32x4 acc[2];
#pragma unroll
            for (int ntl = 0; ntl < 2; ntl++) { f32x4 z = {0.f, 0.f, 0.f, 0.f}; acc[ntl] = z; }

            // acc accumulates over 4 kt-pair intervals (kt 0..7)
#pragma unroll
            for (int q = 0; q < 4; q++) {
                const int s = st * 32 + eb0 * 4 + q;     // interval 0..95
                __syncthreads();                         // drains stage(s)
                if (s + 1 < NSEQ)
                    stage_kt2(wp, ring, ks_of(s + 1, rot), (s + 1) & 1, co, wv, lane);

                const __bf16* buf = ring + ((s & 1) << 12);
#pragma unroll
                for (int j = 0; j < 2; j++) {
                    const int kt = q * 2 + j;
                    const __bf16* reg = buf + (j << 11) + (cgl << 10);
                    bfv8 bv0 = *(const bfv8*)(reg + ((size_t)lane << 3));
                    bfv8 bv1 = *(const bfv8*)(reg + 512 + ((size_t)lane << 3));
                    acc[0] = __builtin_amdgcn_mfma_f32_16x16x32_bf16(afr2[kt], bv0, acc[0], 0, 0, 0);
                    acc[1] = __builtin_amdgcn_mfma_f32_16x16x32_bf16(afr2[kt], bv1, acc[1], 0, 0, 0);
                }
            }

            // bias (per output column)
#pragma unroll
            for (int r = 0; r < 4; r++) { acc[0][r] += b0; acc[1][r] += b1; }

            // gated fold. Gate table columns: a:0-15, b:16-31, s:32-55.
            if (st == 0)      { FOLD(0, 0);  FOLD(2, 32); }
            else if (st == 1) { FOLD(1, 16); FOLD(2, 40); }
            else              { FOLD(0, 8);  FOLD(1, 24); FOLD(2, 48); }
        }
    }
#undef FOLD

    // ---------------- epilogue: store 3 outputs (nontemporal) (R11) -----------
#pragma unroll
    for (int oi = 0; oi < 3; oi++) {
        float* ob = out + (size_t)oi * BATCH * DDIM;
#pragma unroll
        for (int r = 0; r < 4; r++) {
            int row = rbase + quad * 4 + r;
#pragma unroll
            for (int ntl = 0; ntl < 2; ntl++)
                __builtin_nontemporal_store(o[oi][ntl][r],
                    &ob[(size_t)row * DDIM + co * 64 + cgl * 32 + ntl * 16 + l16]);
        }
    }
}

extern "C" void kernel_launch(void* const* d_in, const int* in_sizes, int n_in,
                              void* d_out, int out_size, void* d_ws, size_t ws_size,
                              hipStream_t stream) {
    const float* xa = (const float*)d_in[0];
    const float* xb = (const float*)d_in[1];
    const float* xs = (const float*)d_in[2];
    const float* Wa = (const float*)d_in[3];
    const float* ba = (const float*)d_in[4];
    const float* Wb = (const float*)d_in[5];
    const float* bb = (const float*)d_in[6];
    const float* Ws = (const float*)d_in[7];
    const float* bs = (const float*)d_in[8];
    const float* Ga = (const float*)d_in[9];
    const float* Gb = (const float*)d_in[10];
    const float* Gs = (const float*)d_in[11];

    __bf16* wp = (__bf16*)d_ws;                 // 1.5 MB packed expert weights
    __bf16* gp = wp + 3 * 8 * 8 * 8 * 64 * 8;   // 32 KB packed gate matrix

    prep_kernel<<<200, 256, 0, stream>>>(Wa, Wb, Ws, Ga, Gb, Gs, wp, gp);
    ple_kernel<<<2 * (BATCH / ROWS), THREADS, 0, stream>>>(xa, xb, xs, ba, bb, bs, wp, gp, (float*)d_out);
}

// Round 18
// 194.682 us; speedup vs baseline: 1.1182x; 1.0056x over previous
//
#include <hip/hip_runtime.h>
#include <stdint.h>

// Problem constants
#define BATCH 16384
#define INDIM 256
#define DDIM  128
#define NEXP  8
#define ROWS  128         // batch rows per block (halves weight traffic vs 64)
#define THREADS 512       // 8 waves
#define NSEQ  96          // staging intervals: (st, eb0, q) kt-pair x col-half
#define QSLB  4096        // bf16 elems staged per interval (8 KB)

typedef __bf16 bfv8  __attribute__((ext_vector_type(8)));   // MFMA A/B frag: 8 bf16 = 4 VGPRs
typedef float  f32x4 __attribute__((ext_vector_type(4)));   // MFMA C/D frag

typedef __attribute__((address_space(1))) const void gas_void;
typedef __attribute__((address_space(3))) void las_void;

// ---------------------------------------------------------------------------
// Prep kernel (R7 version, unchanged, passing): coalesced repack of Wa/Wb/Ws
// and gate matrices into bf16 MFMA B-fragment layout. Contract:
//   wp + g*4096 + nt*512 + lane*8 + j = (bf16) W_st[e*256 + kt*32 +
//     (lane>>4)*8 + j][nt*16 + (lane&15)],  g = st*64 + e*8 + kt.
// ---------------------------------------------------------------------------
__global__ void prep_kernel(const float* __restrict__ Wa, const float* __restrict__ Wb,
                            const float* __restrict__ Ws, const float* __restrict__ Ga,
                            const float* __restrict__ Gb, const float* __restrict__ Gs,
                            __bf16* __restrict__ wp, __bf16* __restrict__ gp) {
    __shared__ float ws[32 * 132];          // 32 rows x 128 cols, pad 4
    const int b = blockIdx.x, tid = threadIdx.x;
    if (b < 192) {
        const int st = b >> 6, e = (b >> 3) & 7, kt = b & 7;
        const float* W = (st == 0) ? Wa : (st == 1) ? Wb : Ws;
        const float* src = W + (size_t)(e * 256 + kt * 32) * 128;
#pragma unroll
        for (int k = 0; k < 4; k++) {
            int idx4 = tid + k * 256;
            f32x4 v = *(const f32x4*)(src + (size_t)idx4 * 4);
            int row = idx4 >> 5;
            int col = (idx4 & 31) << 2;
            ws[row * 132 + col + 0] = v[0];
            ws[row * 132 + col + 1] = v[1];
            ws[row * 132 + col + 2] = v[2];
            ws[row * 132 + col + 3] = v[3];
        }
        __syncthreads();
        __bf16* o = wp + ((size_t)b << 12);
#pragma unroll
        for (int h2 = 0; h2 < 2; h2++) {
            int base = tid * 2 + h2;
            int nt = base >> 6, lane = base & 63;
            int d  = nt * 16 + (lane & 15);
            int i0 = (lane >> 4) * 8;
            bfv8 ov;
#pragma unroll
            for (int j = 0; j < 8; j++) ov[j] = (__bf16)ws[(i0 + j) * 132 + d];
            *(bfv8*)(o + (size_t)base * 8) = ov;
        }
    } else {
        int t2 = (b - 192) * 256 + tid;
        int lane = t2 & 63, nt = (t2 >> 6) & 3, kt = t2 >> 8;
        int g  = nt * 16 + (lane & 15);
        int k0 = kt * 32 + (lane >> 4) * 8;
        __bf16* o = gp + (size_t)t2 * 8;
#pragma unroll
        for (int j = 0; j < 8; j++) {
            int k = k0 + j;
            float v = 0.f;
            if (g < 16)      v = Ga[g * 256 + k];
            else if (g < 32) v = Gb[(g - 16) * 256 + k];
            else if (g < 56) v = Gs[(g - 32) * 256 + k];
            o[j] = (__bf16)v;
        }
    }
}

// A fragments (2 row-tiles x 8 k-tiles), fp32->bf16, nontemporal (R7).
__device__ __forceinline__ void load_afr(const float* __restrict__ x, int rb,
                                         int l16, int quad, bfv8 afr[2][8]) {
#pragma unroll
    for (int mt = 0; mt < 2; mt++) {
        const float* xr = x + (size_t)(rb + mt * 16 + l16) * INDIM;
#pragma unroll
        for (int kt = 0; kt < 8; kt++) {
            const f32x4* p = (const f32x4*)(xr + kt * 32 + quad * 8);
            f32x4 lo = __builtin_nontemporal_load(p);
            f32x4 hi = __builtin_nontemporal_load(p + 1);
            bfv8 a;
            a[0] = (__bf16)lo[0]; a[1] = (__bf16)lo[1]; a[2] = (__bf16)lo[2]; a[3] = (__bf16)lo[3];
            a[4] = (__bf16)hi[0]; a[5] = (__bf16)hi[1]; a[6] = (__bf16)hi[2]; a[7] = (__bf16)hi[3];
            afr[mt][kt] = a;
        }
    }
}

// Stage one interval: kt-pair x block's 64-col half = 4096 elems (8 KB).
// 8 waves x 1 gll of 1KB (R12, unchanged). Wave wv covers elems [wv*512,+512).
__device__ __forceinline__ void stage_kt2(const __bf16* __restrict__ wp,
                                          __bf16* ring, int ks, int slot,
                                          int co, int wv, int lane) {
    const __bf16* src = wp + ((size_t)(ks + (wv >> 2)) << 12)
                           + (co << 11) + ((wv & 3) << 9) + (lane << 3);
    __bf16* dst = ring + (slot << 12) + ((size_t)wv << 9);
    __builtin_amdgcn_global_load_lds((gas_void*)src, (las_void*)dst, 16, 0, 0);
}

// Rotation (R7, +4-5% proven): interval s = st*32 + eb0*4 + q -> physical
// base kt-slab st*64 + eb*8 + q*2, eb = (eb0+rot)&7.
__device__ __forceinline__ int ks_of(int s, int rot) {
    int st = s >> 5;
    int eb = (((s >> 2) & 7) + rot) & 7;
    return st * 64 + eb * 8 + (s & 3) * 2;
}

// ---------------------------------------------------------------------------
// Main fused kernel R13: HALVE per-CU weight traffic. All-rounds fit: per-CU
// staged bytes is the only strong lever (NSEQ 48/96/192 invariant; occupancy
// 2x = +18% (R12); bytes 2x = +40% (R8); R4 register path 35 GB/s/CU).
// ROWS 64 -> 128 with col-split retained: grid 256 = 128 rowblks x 2 halves,
// 0.75 MB weight reads per block -> 192 MB total (half of ALL prior rounds).
// Staging cadence byte-identical to R12 (passed). Phase 2: 4 rg x 2 cgl,
// wave = 32 rows x 32 cols (R7's proven afr[2][8] + o[3][2][2][4] layout).
// Phase 1 = R7's loop run twice (pass 0/1 over 64-row halves). Softmax over
// 128 rows. LDS: ring 16 + lgt 32 + wT 32 = 80 KB -> 1 block/CU (trades
// R12's +18% TLP for -50% bytes; comparator is R11: 1 blk/CU, 2x bytes, 115us).
// ---------------------------------------------------------------------------
__launch_bounds__(THREADS, 2)
__global__ void ple_kernel(const float* __restrict__ xa, const float* __restrict__ xb,
                           const float* __restrict__ xs,
                           const float* __restrict__ ba, const float* __restrict__ bb,
                           const float* __restrict__ bs,
                           const __bf16* __restrict__ wp, const __bf16* __restrict__ gp,
                           float* __restrict__ out) {
    __shared__ __bf16 ring[2 * QSLB];       // 16 KB double-buffered interval
    __shared__ float lgt[ROWS * 64];        // 32 KB logits [row][gate]
    __shared__ float wT[64 * ROWS];         // 32 KB softmax weights [gate][row]

    const int tid  = threadIdx.x;
    const int wv   = tid >> 6;        // wave id 0..7
    const int lane = tid & 63;
    const int quad = lane >> 4;
    const int l16  = lane & 15;
    const int bid  = blockIdx.x;
    const int r0   = (bid >> 1) * ROWS;   // row block (128 rows)
    const int co   = bid & 1;             // column half 0..1 (cols co*64..+64)
    const int rot  = (bid >> 3) & 7;

    // Prologue: stage interval 0 into slot 0; completes under phase 1's
    // __syncthreads (vmcnt drained at barrier).
    stage_kt2(wp, ring, ks_of(0, rot), 0, co, wv, lane);

    // ---------------- Phase 1: gate logits via MFMA (R7 loop x 2 passes) ----
    {
        const int rg = wv >> 2;           // 0..1 (32-row groups within pass)
        const int cg = wv & 3;            // 0..3 (16-gate groups)
        const float* x = (cg == 0) ? xa : (cg == 1) ? xb : xs;  // wave-uniform
        bfv8 afr[2][8];
#pragma unroll
        for (int pass = 0; pass < 2; pass++) {
            const int rb = r0 + pass * 64 + rg * 32;
            load_afr(x, rb, l16, quad, afr);
            f32x4 acc1[2];
#pragma unroll
            for (int mt = 0; mt < 2; mt++) { f32x4 z = {0.f, 0.f, 0.f, 0.f}; acc1[mt] = z; }
#pragma unroll
            for (int kt = 0; kt < 8; kt++) {
                bfv8 gfr = *(const bfv8*)(gp + ((size_t)(kt * 4 + cg) * 64 + lane) * 8);
#pragma unroll
                for (int mt = 0; mt < 2; mt++)
                    acc1[mt] = __builtin_amdgcn_mfma_f32_16x16x32_bf16(afr[mt][kt], gfr, acc1[mt], 0, 0, 0);
            }
#pragma unroll
            for (int mt = 0; mt < 2; mt++)
#pragma unroll
                for (int r = 0; r < 4; r++)
                    lgt[(pass * 64 + rg * 32 + mt * 16 + quad * 4 + r) * 64 + cg * 16 + l16] = acc1[mt][r];
        }
    }
    __syncthreads();

    // ---------------- softmax per row (128 rows) ----------------
    if (tid < ROWS) {
        const float* L = lgt + tid * 64;
#pragma unroll
        for (int gi = 0; gi < 3; gi++) {
            const int base = (gi == 0) ? 0 : (gi == 1 ? 16 : 32);
            const int cnt  = (gi == 2) ? 24 : 16;
            float m = -1e30f;
            for (int k = 0; k < cnt; k++) m = fmaxf(m, L[base + k]);
            float s = 0.f;
            for (int k = 0; k < cnt; k++) s += __expf(L[base + k] - m);
            float inv = 1.f / s;
            for (int k = 0; k < cnt; k++) wT[(base + k) * ROWS + tid] = __expf(L[base + k] - m) * inv;
        }
    }
    __syncthreads();

    // ---------------- Phase 2: experts, waves 4rg2 x 2cgl --------------------
    const int rg2   = wv >> 1;        // 0..3: 32-row tile
    const int cgl   = wv & 1;         // 0..1: 32-col tile within block's half
    const int rbase = r0 + rg2 * 32;

    bfv8 afr2[2][8];
    float o[3][2][2][4];              // [out][mt][ntl][reg]
#pragma unroll
    for (int oi = 0; oi < 3; oi++)
#pragma unroll
        for (int mt = 0; mt < 2; mt++)
#pragma unroll
            for (int ntl = 0; ntl < 2; ntl++)
#pragma unroll
                for (int r = 0; r < 4; r++) o[oi][mt][ntl][r] = 0.f;

#define FOLD(oi, gbase)                                                                 \
    {                                                                                   \
        _Pragma("unroll")                                                               \
        for (int mt = 0; mt < 2; mt++) {                                                \
            f32x4 gw4 = *(const f32x4*)(wT + (gbase + eb) * ROWS + rg2 * 32 + mt * 16 + quad * 4); \
            _Pragma("unroll")                                                           \
            for (int ntl = 0; ntl < 2; ntl++)                                           \
                _Pragma("unroll")                                                       \
                for (int r = 0; r < 4; r++)                                             \
                    o[oi][mt][ntl][r] += gw4[r] * acc[mt][ntl][r];                      \
        }                                                                               \
    }

#pragma unroll
    for (int st = 0; st < 3; st++) {
        const float* x    = (st == 0) ? xa : (st == 1) ? xb : xs;
        const float* bias = (st == 0) ? ba : (st == 1) ? bb : bs;
        load_afr(x, rbase, l16, quad, afr2);

#pragma unroll 1
        for (int eb0 = 0; eb0 < NEXP; eb0++) {
            const int eb = (eb0 + rot) & 7;
            float b0 = bias[eb * 128 + co * 64 + cgl * 32 + l16];
            float b1 = bias[eb * 128 + co * 64 + cgl * 32 + 16 + l16];

            f32x4 acc[2][2];
#pragma unroll
            for (int mt = 0; mt < 2; mt++)
#pragma unroll
                for (int ntl = 0; ntl < 2; ntl++) { f32x4 z = {0.f, 0.f, 0.f, 0.f}; acc[mt][ntl] = z; }

            // acc accumulates over 4 kt-pair intervals (kt 0..7)
#pragma unroll
            for (int q = 0; q < 4; q++) {
                const int s = st * 32 + eb0 * 4 + q;     // interval 0..95
                __syncthreads();                         // drains stage(s)
                if (s + 1 < NSEQ)
                    stage_kt2(wp, ring, ks_of(s + 1, rot), (s + 1) & 1, co, wv, lane);

                const __bf16* buf = ring + ((s & 1) << 12);
#pragma unroll
                for (int j = 0; j < 2; j++) {
                    const int kt = q * 2 + j;
                    const __bf16* reg = buf + (j << 11) + (cgl << 10);
                    bfv8 bv0 = *(const bfv8*)(reg + ((size_t)lane << 3));
                    bfv8 bv1 = *(const bfv8*)(reg + 512 + ((size_t)lane << 3));
                    acc[0][0] = __builtin_amdgcn_mfma_f32_16x16x32_bf16(afr2[0][kt], bv0, acc[0][0], 0, 0, 0);
                    acc[1][0] = __builtin_amdgcn_mfma_f32_16x16x32_bf16(afr2[1][kt], bv0, acc[1][0], 0, 0, 0);
                    acc[0][1] = __builtin_amdgcn_mfma_f32_16x16x32_bf16(afr2[0][kt], bv1, acc[0][1], 0, 0, 0);
                    acc[1][1] = __builtin_amdgcn_mfma_f32_16x16x32_bf16(afr2[1][kt], bv1, acc[1][1], 0, 0, 0);
                }
            }

            // bias (per output column)
#pragma unroll
            for (int mt = 0; mt < 2; mt++)
#pragma unroll
                for (int r = 0; r < 4; r++) { acc[mt][0][r] += b0; acc[mt][1][r] += b1; }

            // gated fold. Gate table columns: a:0-15, b:16-31, s:32-55.
            if (st == 0)      { FOLD(0, 0);  FOLD(2, 32); }
            else if (st == 1) { FOLD(1, 16); FOLD(2, 40); }
            else              { FOLD(0, 8);  FOLD(1, 24); FOLD(2, 48); }
        }
    }
#undef FOLD

    // ---------------- epilogue: store 3 outputs (nontemporal) ----------------
#pragma unroll
    for (int oi = 0; oi < 3; oi++) {
        float* ob = out + (size_t)oi * BATCH * DDIM;
#pragma unroll
        for (int mt = 0; mt < 2; mt++)
#pragma unroll
            for (int r = 0; r < 4; r++) {
                int row = rbase + mt * 16 + quad * 4 + r;
#pragma unroll
                for (int ntl = 0; ntl < 2; ntl++)
                    __builtin_nontemporal_store(o[oi][mt][ntl][r],
                        &ob[(size_t)row * DDIM + co * 64 + cgl * 32 + ntl * 16 + l16]);
            }
    }
}

extern "C" void kernel_launch(void* const* d_in, const int* in_sizes, int n_in,
                              void* d_out, int out_size, void* d_ws, size_t ws_size,
                              hipStream_t stream) {
    const float* xa = (const float*)d_in[0];
    const float* xb = (const float*)d_in[1];
    const float* xs = (const float*)d_in[2];
    const float* Wa = (const float*)d_in[3];
    const float* ba = (const float*)d_in[4];
    const float* Wb = (const float*)d_in[5];
    const float* bb = (const float*)d_in[6];
    const float* Ws = (const float*)d_in[7];
    const float* bs = (const float*)d_in[8];
    const float* Ga = (const float*)d_in[9];
    const float* Gb = (const float*)d_in[10];
    const float* Gs = (const float*)d_in[11];

    __bf16* wp = (__bf16*)d_ws;                 // 1.5 MB packed expert weights
    __bf16* gp = wp + 3 * 8 * 8 * 8 * 64 * 8;   // 32 KB packed gate matrix

    prep_kernel<<<200, 256, 0, stream>>>(Wa, Wb, Ws, Ga, Gb, Gs, wp, gp);
    ple_kernel<<<2 * (BATCH / ROWS), THREADS, 0, stream>>>(xa, xb, xs, ba, bb, bs, wp, gp, (float*)d_out);
}

// Round 19
// 175.920 us; speedup vs baseline: 1.2374x; 1.1066x over previous
//
#include <hip/hip_runtime.h>
#include <stdint.h>

// Problem constants
#define BATCH 16384
#define INDIM 256
#define DDIM  128
#define NEXP  8
#define ROWS  64          // batch rows per block
#define THREADS 512       // 8 waves
#define NSEQ  96          // staging intervals: (st, eb0, q) kt-pair x col-half
#define QSLB  4096        // bf16 elems staged per interval (8 KB)

typedef __bf16 bfv8  __attribute__((ext_vector_type(8)));   // MFMA A/B frag: 8 bf16 = 4 VGPRs
typedef float  f32x4 __attribute__((ext_vector_type(4)));   // MFMA C/D frag

typedef __attribute__((address_space(1))) const void gas_void;
typedef __attribute__((address_space(3))) void las_void;

// ---------------------------------------------------------------------------
// Prep kernel (R7 version, unchanged, passing): coalesced repack of Wa/Wb/Ws
// and gate matrices into bf16 MFMA B-fragment layout. Contract:
//   wp + g*4096 + nt*512 + lane*8 + j = (bf16) W_st[e*256 + kt*32 +
//     (lane>>4)*8 + j][nt*16 + (lane&15)],  g = st*64 + e*8 + kt.
// ---------------------------------------------------------------------------
__global__ void prep_kernel(const float* __restrict__ Wa, const float* __restrict__ Wb,
                            const float* __restrict__ Ws, const float* __restrict__ Ga,
                            const float* __restrict__ Gb, const float* __restrict__ Gs,
                            __bf16* __restrict__ wp, __bf16* __restrict__ gp) {
    __shared__ float ws[32 * 132];          // 32 rows x 128 cols, pad 4
    const int b = blockIdx.x, tid = threadIdx.x;
    if (b < 192) {
        const int st = b >> 6, e = (b >> 3) & 7, kt = b & 7;
        const float* W = (st == 0) ? Wa : (st == 1) ? Wb : Ws;
        const float* src = W + (size_t)(e * 256 + kt * 32) * 128;
#pragma unroll
        for (int k = 0; k < 4; k++) {
            int idx4 = tid + k * 256;
            f32x4 v = *(const f32x4*)(src + (size_t)idx4 * 4);
            int row = idx4 >> 5;
            int col = (idx4 & 31) << 2;
            ws[row * 132 + col + 0] = v[0];
            ws[row * 132 + col + 1] = v[1];
            ws[row * 132 + col + 2] = v[2];
            ws[row * 132 + col + 3] = v[3];
        }
        __syncthreads();
        __bf16* o = wp + ((size_t)b << 12);
#pragma unroll
        for (int h2 = 0; h2 < 2; h2++) {
            int base = tid * 2 + h2;
            int nt = base >> 6, lane = base & 63;
            int d  = nt * 16 + (lane & 15);
            int i0 = (lane >> 4) * 8;
            bfv8 ov;
#pragma unroll
            for (int j = 0; j < 8; j++) ov[j] = (__bf16)ws[(i0 + j) * 132 + d];
            *(bfv8*)(o + (size_t)base * 8) = ov;
        }
    } else {
        int t2 = (b - 192) * 256 + tid;
        int lane = t2 & 63, nt = (t2 >> 6) & 3, kt = t2 >> 8;
        int g  = nt * 16 + (lane & 15);
        int k0 = kt * 32 + (lane >> 4) * 8;
        __bf16* o = gp + (size_t)t2 * 8;
#pragma unroll
        for (int j = 0; j < 8; j++) {
            int k = k0 + j;
            float v = 0.f;
            if (g < 16)      v = Ga[g * 256 + k];
            else if (g < 32) v = Gb[(g - 16) * 256 + k];
            else if (g < 56) v = Gs[(g - 32) * 256 + k];
            o[j] = (__bf16)v;
        }
    }
}

// Phase-1 A fragments (2 row-tiles x 8 k-tiles), fp32->bf16. R14: PLAIN loads
// (nontemporal removed) -- with col-split, each x row is read by 2 blocks;
// NT loads bypassed L3 so the second read hit HBM (FETCH 66->110MB, the +32us
// col-split penalty R7->R11). Plain loads let L3/L2 serve the sibling's read.
__device__ __forceinline__ void load_afr(const float* __restrict__ x, int rb,
                                         int l16, int quad, bfv8 afr[2][8]) {
#pragma unroll
    for (int mt = 0; mt < 2; mt++) {
        const float* xr = x + (size_t)(rb + mt * 16 + l16) * INDIM;
#pragma unroll
        for (int kt = 0; kt < 8; kt++) {
            f32x4 lo = *(const f32x4*)(xr + kt * 32 + quad * 8);
            f32x4 hi = *(const f32x4*)(xr + kt * 32 + quad * 8 + 4);
            bfv8 a;
            a[0] = (__bf16)lo[0]; a[1] = (__bf16)lo[1]; a[2] = (__bf16)lo[2]; a[3] = (__bf16)lo[3];
            a[4] = (__bf16)hi[0]; a[5] = (__bf16)hi[1]; a[6] = (__bf16)hi[2]; a[7] = (__bf16)hi[3];
            afr[mt][kt] = a;
        }
    }
}

// Phase-2 A fragments (ONE 16-row tile x 8 k-tiles). Plain loads (see above).
__device__ __forceinline__ void load_afr16(const float* __restrict__ x, int rbase,
                                           int l16, int quad, bfv8 afr[8]) {
    const float* xr = x + (size_t)(rbase + l16) * INDIM;
#pragma unroll
    for (int kt = 0; kt < 8; kt++) {
        f32x4 lo = *(const f32x4*)(xr + kt * 32 + quad * 8);
        f32x4 hi = *(const f32x4*)(xr + kt * 32 + quad * 8 + 4);
        bfv8 a;
        a[0] = (__bf16)lo[0]; a[1] = (__bf16)lo[1]; a[2] = (__bf16)lo[2]; a[3] = (__bf16)lo[3];
        a[4] = (__bf16)hi[0]; a[5] = (__bf16)hi[1]; a[6] = (__bf16)hi[2]; a[7] = (__bf16)hi[3];
        afr[kt] = a;
    }
}

// Stage one interval: kt-pair x block's 64-col half = 4096 elems (8 KB).
// 8 waves x 1 gll of 1KB (R12, unchanged). Wave wv covers elems [wv*512,+512).
__device__ __forceinline__ void stage_kt2(const __bf16* __restrict__ wp,
                                          __bf16* ring, int ks, int slot,
                                          int co, int wv, int lane) {
    const __bf16* src = wp + ((size_t)(ks + (wv >> 2)) << 12)
                           + (co << 11) + ((wv & 3) << 9) + (lane << 3);
    __bf16* dst = ring + (slot << 12) + ((size_t)wv << 9);
    __builtin_amdgcn_global_load_lds((gas_void*)src, (las_void*)dst, 16, 0, 0);
}

// Rotation (R7, +4-5% proven): interval s = st*32 + eb0*4 + q -> physical
// base kt-slab st*64 + eb*8 + q*2, eb = (eb0+rot)&7.
__device__ __forceinline__ int ks_of(int s, int rot) {
    int st = s >> 5;
    int eb = (((s >> 2) & 7) + rot) & 7;
    return st * 64 + eb * 8 + (s & 3) * 2;
}

// ---------------------------------------------------------------------------
// Main fused kernel R14 = R12 (passing, 97.5us, 40% occupancy) with ONE
// change: nontemporal removed from x loads. R13 post-mortem refuted the
// per-CU-traffic model (halved bytes -> 103us); the dominant unexplained
// term is the col-split's +32us whose signature is FETCH 66->110MB: NT x
// loads bypass L3, so the col-sibling block's re-read of the same x rows
// goes to HBM. Plain loads restore L3 service. NT *stores* kept (outputs
// never re-read). All structure identical to R12: grid 512 (rowblk x
// col-half), 48KB LDS -> 2 blocks/CU = 16 waves/CU, NSEQ 96, rotation.
// ---------------------------------------------------------------------------
__launch_bounds__(THREADS, 2)
__global__ void ple_kernel(const float* __restrict__ xa, const float* __restrict__ xb,
                           const float* __restrict__ xs,
                           const float* __restrict__ ba, const float* __restrict__ bb,
                           const float* __restrict__ bs,
                           const __bf16* __restrict__ wp, const __bf16* __restrict__ gp,
                           float* __restrict__ out) {
    __shared__ __bf16 ring[2 * QSLB];       // 16 KB double-buffered interval
    __shared__ float lgt[ROWS * 64];        // 16 KB logits [row][gate]
    __shared__ float wT[64 * ROWS];         // 16 KB softmax weights [gate][row]

    const int tid  = threadIdx.x;
    const int wv   = tid >> 6;        // wave id 0..7
    const int lane = tid & 63;
    const int quad = lane >> 4;
    const int l16  = lane & 15;
    const int bid  = blockIdx.x;
    const int r0   = (bid >> 1) * ROWS;   // row block
    const int co   = bid & 1;             // column half 0..1 (cols co*64..+64)
    const int rot  = (bid >> 3) & 7;

    // Prologue: stage interval 0 into slot 0; completes under phase 1's
    // __syncthreads (vmcnt drained at barrier).
    stage_kt2(wp, ring, ks_of(0, rot), 0, co, wv, lane);

    // ---------------- Phase 1: gate logits via MFMA (R12, unchanged) --------
    {
        const int rg = wv >> 2;           // 0..1 (32-row groups)
        const int cg = wv & 3;            // 0..3 (16-gate groups)
        const int rb = r0 + rg * 32;
        bfv8 afr[2][8];
        const float* x = (cg == 0) ? xa : (cg == 1) ? xb : xs;  // wave-uniform
        load_afr(x, rb, l16, quad, afr);
        f32x4 acc1[2];
#pragma unroll
        for (int mt = 0; mt < 2; mt++) { f32x4 z = {0.f, 0.f, 0.f, 0.f}; acc1[mt] = z; }
#pragma unroll
        for (int kt = 0; kt < 8; kt++) {
            bfv8 gfr = *(const bfv8*)(gp + ((size_t)(kt * 4 + cg) * 64 + lane) * 8);
#pragma unroll
            for (int mt = 0; mt < 2; mt++)
                acc1[mt] = __builtin_amdgcn_mfma_f32_16x16x32_bf16(afr[mt][kt], gfr, acc1[mt], 0, 0, 0);
        }
#pragma unroll
        for (int mt = 0; mt < 2; mt++)
#pragma unroll
            for (int r = 0; r < 4; r++)
                lgt[(rg * 32 + mt * 16 + quad * 4 + r) * 64 + cg * 16 + l16] = acc1[mt][r];
    }
    __syncthreads();

    // ---------------- softmax per row (64 rows, one wave) (R12) ---------------
    if (tid < ROWS) {
        const float* L = lgt + tid * 64;
#pragma unroll
        for (int gi = 0; gi < 3; gi++) {
            const int base = (gi == 0) ? 0 : (gi == 1 ? 16 : 32);
            const int cnt  = (gi == 2) ? 24 : 16;
            float m = -1e30f;
            for (int k = 0; k < cnt; k++) m = fmaxf(m, L[base + k]);
            float s = 0.f;
            for (int k = 0; k < cnt; k++) s += __expf(L[base + k] - m);
            float inv = 1.f / s;
            for (int k = 0; k < cnt; k++) wT[(base + k) * ROWS + tid] = __expf(L[base + k] - m) * inv;
        }
    }
    __syncthreads();

    // ---------------- Phase 2: experts, waves 4rg x 2cgl (R12) ---------------
    const int rg2   = wv >> 1;        // 0..3: 16-row tile
    const int cgl   = wv & 1;         // 0..1: 32-col tile within block's half
    const int rbase = r0 + rg2 * 16;

    bfv8 afr2[8];
    float o[3][2][4];                 // [out][ntl][reg]
#pragma unroll
    for (int oi = 0; oi < 3; oi++)
#pragma unroll
        for (int ntl = 0; ntl < 2; ntl++)
#pragma unroll
            for (int r = 0; r < 4; r++) o[oi][ntl][r] = 0.f;

#define FOLD(oi, gbase)                                                              \
    {                                                                                \
        f32x4 gw4 = *(const f32x4*)(wT + (gbase + eb) * ROWS + rg2 * 16 + quad * 4); \
        _Pragma("unroll")                                                            \
        for (int ntl = 0; ntl < 2; ntl++)                                            \
            _Pragma("unroll")                                                        \
            for (int r = 0; r < 4; r++)                                              \
                o[oi][ntl][r] += gw4[r] * acc[ntl][r];                               \
    }

#pragma unroll
    for (int st = 0; st < 3; st++) {
        const float* x    = (st == 0) ? xa : (st == 1) ? xb : xs;
        const float* bias = (st == 0) ? ba : (st == 1) ? bb : bs;
        load_afr16(x, rbase, l16, quad, afr2);

#pragma unroll 1
        for (int eb0 = 0; eb0 < NEXP; eb0++) {
            const int eb = (eb0 + rot) & 7;
            float b0 = bias[eb * 128 + co * 64 + cgl * 32 + l16];
            float b1 = bias[eb * 128 + co * 64 + cgl * 32 + 16 + l16];

            f32x4 acc[2];
#pragma unroll
            for (int ntl = 0; ntl < 2; ntl++) { f32x4 z = {0.f, 0.f, 0.f, 0.f}; acc[ntl] = z; }

            // acc accumulates over 4 kt-pair intervals (kt 0..7)
#pragma unroll
            for (int q = 0; q < 4; q++) {
                const int s = st * 32 + eb0 * 4 + q;     // interval 0..95
                __syncthreads();                         // drains stage(s)
                if (s + 1 < NSEQ)
                    stage_kt2(wp, ring, ks_of(s + 1, rot), (s + 1) & 1, co, wv, lane);

                const __bf16* buf = ring + ((s & 1) << 12);
#pragma unroll
                for (int j = 0; j < 2; j++) {
                    const int kt = q * 2 + j;
                    const __bf16* reg = buf + (j << 11) + (cgl << 10);
                    bfv8 bv0 = *(const bfv8*)(reg + ((size_t)lane << 3));
                    bfv8 bv1 = *(const bfv8*)(reg + 512 + ((size_t)lane << 3));
                    acc[0] = __builtin_amdgcn_mfma_f32_16x16x32_bf16(afr2[kt], bv0, acc[0], 0, 0, 0);
                    acc[1] = __builtin_amdgcn_mfma_f32_16x16x32_bf16(afr2[kt], bv1, acc[1], 0, 0, 0);
                }
            }

            // bias (per output column)
#pragma unroll
            for (int r = 0; r < 4; r++) { acc[0][r] += b0; acc[1][r] += b1; }

            // gated fold. Gate table columns: a:0-15, b:16-31, s:32-55.
            if (st == 0)      { FOLD(0, 0);  FOLD(2, 32); }
            else if (st == 1) { FOLD(1, 16); FOLD(2, 40); }
            else              { FOLD(0, 8);  FOLD(1, 24); FOLD(2, 48); }
        }
    }
#undef FOLD

    // ---------------- epilogue: store 3 outputs (nontemporal) (R12) -----------
#pragma unroll
    for (int oi = 0; oi < 3; oi++) {
        float* ob = out + (size_t)oi * BATCH * DDIM;
#pragma unroll
        for (int r = 0; r < 4; r++) {
            int row = rbase + quad * 4 + r;
#pragma unroll
            for (int ntl = 0; ntl < 2; ntl++)
                __builtin_nontemporal_store(o[oi][ntl][r],
                    &ob[(size_t)row * DDIM + co * 64 + cgl * 32 + ntl * 16 + l16]);
        }
    }
}

extern "C" void kernel_launch(void* const* d_in, const int* in_sizes, int n_in,
                              void* d_out, int out_size, void* d_ws, size_t ws_size,
                              hipStream_t stream) {
    const float* xa = (const float*)d_in[0];
    const float* xb = (const float*)d_in[1];
    const float* xs = (const float*)d_in[2];
    const float* Wa = (const float*)d_in[3];
    const float* ba = (const float*)d_in[4];
    const float* Wb = (const float*)d_in[5];
    const float* bb = (const float*)d_in[6];
    const float* Ws = (const float*)d_in[7];
    const float* bs = (const float*)d_in[8];
    const float* Ga = (const float*)d_in[9];
    const float* Gb = (const float*)d_in[10];
    const float* Gs = (const float*)d_in[11];

    __bf16* wp = (__bf16*)d_ws;                 // 1.5 MB packed expert weights
    __bf16* gp = wp + 3 * 8 * 8 * 8 * 64 * 8;   // 32 KB packed gate matrix

    prep_kernel<<<200, 256, 0, stream>>>(Wa, Wb, Ws, Ga, Gb, Gs, wp, gp);
    ple_kernel<<<2 * (BATCH / ROWS), THREADS, 0, stream>>>(xa, xb, xs, ba, bb, bs, wp, gp, (float*)d_out);
}

// Round 20
// 174.962 us; speedup vs baseline: 1.2442x; 1.0055x over previous
//
#include <hip/hip_runtime.h>
#include <stdint.h>

// Problem constants
#define BATCH 16384
#define INDIM 256
#define DDIM  128
#define NEXP  8
#define ROWS  64          // batch rows per block
#define THREADS 512       // 8 waves
#define NSEQ  96          // staging intervals: (st, eb0, q) kt-pair x col-half
#define QSLB  4096        // bf16 elems staged per interval (8 KB)

typedef __bf16 bfv8  __attribute__((ext_vector_type(8)));   // MFMA A/B frag: 8 bf16 = 4 VGPRs
typedef float  f32x4 __attribute__((ext_vector_type(4)));   // MFMA C/D frag

typedef __attribute__((address_space(1))) const void gas_void;
typedef __attribute__((address_space(3))) void las_void;

// ---------------------------------------------------------------------------
// Prep kernel (R7 version, unchanged, passing): coalesced repack of Wa/Wb/Ws
// and gate matrices into bf16 MFMA B-fragment layout. Contract:
//   wp + g*4096 + nt*512 + lane*8 + j = (bf16) W_st[e*256 + kt*32 +
//     (lane>>4)*8 + j][nt*16 + (lane&15)],  g = st*64 + e*8 + kt.
// ---------------------------------------------------------------------------
__global__ void prep_kernel(const float* __restrict__ Wa, const float* __restrict__ Wb,
                            const float* __restrict__ Ws, const float* __restrict__ Ga,
                            const float* __restrict__ Gb, const float* __restrict__ Gs,
                            __bf16* __restrict__ wp, __bf16* __restrict__ gp) {
    __shared__ float ws[32 * 132];          // 32 rows x 128 cols, pad 4
    const int b = blockIdx.x, tid = threadIdx.x;
    if (b < 192) {
        const int st = b >> 6, e = (b >> 3) & 7, kt = b & 7;
        const float* W = (st == 0) ? Wa : (st == 1) ? Wb : Ws;
        const float* src = W + (size_t)(e * 256 + kt * 32) * 128;
#pragma unroll
        for (int k = 0; k < 4; k++) {
            int idx4 = tid + k * 256;
            f32x4 v = *(const f32x4*)(src + (size_t)idx4 * 4);
            int row = idx4 >> 5;
            int col = (idx4 & 31) << 2;
            ws[row * 132 + col + 0] = v[0];
            ws[row * 132 + col + 1] = v[1];
            ws[row * 132 + col + 2] = v[2];
            ws[row * 132 + col + 3] = v[3];
        }
        __syncthreads();
        __bf16* o = wp + ((size_t)b << 12);
#pragma unroll
        for (int h2 = 0; h2 < 2; h2++) {
            int base = tid * 2 + h2;
            int nt = base >> 6, lane = base & 63;
            int d  = nt * 16 + (lane & 15);
            int i0 = (lane >> 4) * 8;
            bfv8 ov;
#pragma unroll
            for (int j = 0; j < 8; j++) ov[j] = (__bf16)ws[(i0 + j) * 132 + d];
            *(bfv8*)(o + (size_t)base * 8) = ov;
        }
    } else {
        int t2 = (b - 192) * 256 + tid;
        int lane = t2 & 63, nt = (t2 >> 6) & 3, kt = t2 >> 8;
        int g  = nt * 16 + (lane & 15);
        int k0 = kt * 32 + (lane >> 4) * 8;
        __bf16* o = gp + (size_t)t2 * 8;
#pragma unroll
        for (int j = 0; j < 8; j++) {
            int k = k0 + j;
            float v = 0.f;
            if (g < 16)      v = Ga[g * 256 + k];
            else if (g < 32) v = Gb[(g - 16) * 256 + k];
            else if (g < 56) v = Gs[(g - 32) * 256 + k];
            o[j] = (__bf16)v;
        }
    }
}

// Phase-1 A fragments (2 row-tiles x 8 k-tiles), fp32->bf16, PLAIN loads
// (R14: NT removal was +16% -- col-sibling re-reads L3/L2-served).
__device__ __forceinline__ void load_afr(const float* __restrict__ x, int rb,
                                         int l16, int quad, bfv8 afr[2][8]) {
#pragma unroll
    for (int mt = 0; mt < 2; mt++) {
        const float* xr = x + (size_t)(rb + mt * 16 + l16) * INDIM;
#pragma unroll
        for (int kt = 0; kt < 8; kt++) {
            f32x4 lo = *(const f32x4*)(xr + kt * 32 + quad * 8);
            f32x4 hi = *(const f32x4*)(xr + kt * 32 + quad * 8 + 4);
            bfv8 a;
            a[0] = (__bf16)lo[0]; a[1] = (__bf16)lo[1]; a[2] = (__bf16)lo[2]; a[3] = (__bf16)lo[3];
            a[4] = (__bf16)hi[0]; a[5] = (__bf16)hi[1]; a[6] = (__bf16)hi[2]; a[7] = (__bf16)hi[3];
            afr[mt][kt] = a;
        }
    }
}

// Phase-2 A fragments (ONE 16-row tile x 8 k-tiles). Plain loads.
__device__ __forceinline__ void load_afr16(const float* __restrict__ x, int rbase,
                                           int l16, int quad, bfv8 afr[8]) {
    const float* xr = x + (size_t)(rbase + l16) * INDIM;
#pragma unroll
    for (int kt = 0; kt < 8; kt++) {
        f32x4 lo = *(const f32x4*)(xr + kt * 32 + quad * 8);
        f32x4 hi = *(const f32x4*)(xr + kt * 32 + quad * 8 + 4);
        bfv8 a;
        a[0] = (__bf16)lo[0]; a[1] = (__bf16)lo[1]; a[2] = (__bf16)lo[2]; a[3] = (__bf16)lo[3];
        a[4] = (__bf16)hi[0]; a[5] = (__bf16)hi[1]; a[6] = (__bf16)hi[2]; a[7] = (__bf16)hi[3];
        afr[kt] = a;
    }
}

// Stage one interval: kt-pair x block's 64-col half = 4096 elems (8 KB).
// 8 waves x 1 gll of 1KB (R12, unchanged). Wave wv covers elems [wv*512,+512).
__device__ __forceinline__ void stage_kt2(const __bf16* __restrict__ wp,
                                          __bf16* ring, int ks, int slot,
                                          int co, int wv, int lane) {
    const __bf16* src = wp + ((size_t)(ks + (wv >> 2)) << 12)
                           + (co << 11) + ((wv & 3) << 9) + (lane << 3);
    __bf16* dst = ring + (slot << 12) + ((size_t)wv << 9);
    __builtin_amdgcn_global_load_lds((gas_void*)src, (las_void*)dst, 16, 0, 0);
}

// Rotation: interval s = st*32 + eb0*4 + q -> physical base kt-slab
// st*64 + eb*8 + q*2, eb = (eb0+rot)&7.
__device__ __forceinline__ int ks_of(int s, int rot) {
    int st = s >> 5;
    int eb = (((s >> 2) & 7) + rot) & 7;
    return st * 64 + eb * 8 + (s & 3) * 2;
}

// ---------------------------------------------------------------------------
// Main fused kernel R15 = R14 (passing, 81.9us best) with ONE change:
// XCD-PAIRING block swizzle. R14's col-siblings (same rows, co=0/1) were
// adjacent bids -> different XCDs (bid%8=XCD) -> sibling x re-reads served
// by L3 (~500cy, FETCH still 98MB vs ideal ~60). Remap so siblings share an
// XCD: xcd=bid&7, co=(bid>>3)&1, rowblk=(bid>>4)*8+xcd (bijective; sibling
// pair differs only in bit 3 -> same XCD; all 512 blocks co-resident at
// 2/CU so both run concurrently). Sibling x reads become same-XCD L2 hits.
// rot=(bid>>4)&7: varies across same-XCD blocks (de-correlates expert
// order), identical for siblings (they read disjoint weight columns).
// All else byte-identical to R14: 48KB LDS -> 2 blocks/CU = 16 waves/CU,
// NSEQ 96, plain x loads, NT stores.
// ---------------------------------------------------------------------------
__launch_bounds__(THREADS, 2)
__global__ void ple_kernel(const float* __restrict__ xa, const float* __restrict__ xb,
                           const float* __restrict__ xs,
                           const float* __restrict__ ba, const float* __restrict__ bb,
                           const float* __restrict__ bs,
                           const __bf16* __restrict__ wp, const __bf16* __restrict__ gp,
                           float* __restrict__ out) {
    __shared__ __bf16 ring[2 * QSLB];       // 16 KB double-buffered interval
    __shared__ float lgt[ROWS * 64];        // 16 KB logits [row][gate]
    __shared__ float wT[64 * ROWS];         // 16 KB softmax weights [gate][row]

    const int tid  = threadIdx.x;
    const int wv   = tid >> 6;        // wave id 0..7
    const int lane = tid & 63;
    const int quad = lane >> 4;
    const int l16  = lane & 15;
    const int bid  = blockIdx.x;
    const int xcd  = bid & 7;
    const int co   = (bid >> 3) & 1;            // column half (cols co*64..+64)
    const int rowblk = (bid >> 4) * 8 + xcd;    // 0..255, sibling-paired per XCD
    const int r0   = rowblk * ROWS;
    const int rot  = (bid >> 4) & 7;

    // Prologue: stage interval 0 into slot 0; completes under phase 1's
    // __syncthreads (vmcnt drained at barrier).
    stage_kt2(wp, ring, ks_of(0, rot), 0, co, wv, lane);

    // ---------------- Phase 1: gate logits via MFMA (R14, unchanged) --------
    {
        const int rg = wv >> 2;           // 0..1 (32-row groups)
        const int cg = wv & 3;            // 0..3 (16-gate groups)
        const int rb = r0 + rg * 32;
        bfv8 afr[2][8];
        const float* x = (cg == 0) ? xa : (cg == 1) ? xb : xs;  // wave-uniform
        load_afr(x, rb, l16, quad, afr);
        f32x4 acc1[2];
#pragma unroll
        for (int mt = 0; mt < 2; mt++) { f32x4 z = {0.f, 0.f, 0.f, 0.f}; acc1[mt] = z; }
#pragma unroll
        for (int kt = 0; kt < 8; kt++) {
            bfv8 gfr = *(const bfv8*)(gp + ((size_t)(kt * 4 + cg) * 64 + lane) * 8);
#pragma unroll
            for (int mt = 0; mt < 2; mt++)
                acc1[mt] = __builtin_amdgcn_mfma_f32_16x16x32_bf16(afr[mt][kt], gfr, acc1[mt], 0, 0, 0);
        }
#pragma unroll
        for (int mt = 0; mt < 2; mt++)
#pragma unroll
            for (int r = 0; r < 4; r++)
                lgt[(rg * 32 + mt * 16 + quad * 4 + r) * 64 + cg * 16 + l16] = acc1[mt][r];
    }
    __syncthreads();

    // ---------------- softmax per row (64 rows, one wave) (R14) ---------------
    if (tid < ROWS) {
        const float* L = lgt + tid * 64;
#pragma unroll
        for (int gi = 0; gi < 3; gi++) {
            const int base = (gi == 0) ? 0 : (gi == 1 ? 16 : 32);
            const int cnt  = (gi == 2) ? 24 : 16;
            float m = -1e30f;
            for (int k = 0; k < cnt; k++) m = fmaxf(m, L[base + k]);
            float s = 0.f;
            for (int k = 0; k < cnt; k++) s += __expf(L[base + k] - m);
            float inv = 1.f / s;
            for (int k = 0; k < cnt; k++) wT[(base + k) * ROWS + tid] = __expf(L[base + k] - m) * inv;
        }
    }
    __syncthreads();

    // ---------------- Phase 2: experts, waves 4rg x 2cgl (R14) ---------------
    const int rg2   = wv >> 1;        // 0..3: 16-row tile
    const int cgl   = wv & 1;         // 0..1: 32-col tile within block's half
    const int rbase = r0 + rg2 * 16;

    bfv8 afr2[8];
    float o[3][2][4];                 // [out][ntl][reg]
#pragma unroll
    for (int oi = 0; oi < 3; oi++)
#pragma unroll
        for (int ntl = 0; ntl < 2; ntl++)
#pragma unroll
            for (int r = 0; r < 4; r++) o[oi][ntl][r] = 0.f;

#define FOLD(oi, gbase)                                                              \
    {                                                                                \
        f32x4 gw4 = *(const f32x4*)(wT + (gbase + eb) * ROWS + rg2 * 16 + quad * 4); \
        _Pragma("unroll")                                                            \
        for (int ntl = 0; ntl < 2; ntl++)                                            \
            _Pragma("unroll")                                                        \
            for (int r = 0; r < 4; r++)                                              \
                o[oi][ntl][r] += gw4[r] * acc[ntl][r];                               \
    }

#pragma unroll
    for (int st = 0; st < 3; st++) {
        const float* x    = (st == 0) ? xa : (st == 1) ? xb : xs;
        const float* bias = (st == 0) ? ba : (st == 1) ? bb : bs;
        load_afr16(x, rbase, l16, quad, afr2);

#pragma unroll 1
        for (int eb0 = 0; eb0 < NEXP; eb0++) {
            const int eb = (eb0 + rot) & 7;
            float b0 = bias[eb * 128 + co * 64 + cgl * 32 + l16];
            float b1 = bias[eb * 128 + co * 64 + cgl * 32 + 16 + l16];

            f32x4 acc[2];
#pragma unroll
            for (int ntl = 0; ntl < 2; ntl++) { f32x4 z = {0.f, 0.f, 0.f, 0.f}; acc[ntl] = z; }

            // acc accumulates over 4 kt-pair intervals (kt 0..7)
#pragma unroll
            for (int q = 0; q < 4; q++) {
                const int s = st * 32 + eb0 * 4 + q;     // interval 0..95
                __syncthreads();                         // drains stage(s)
                if (s + 1 < NSEQ)
                    stage_kt2(wp, ring, ks_of(s + 1, rot), (s + 1) & 1, co, wv, lane);

                const __bf16* buf = ring + ((s & 1) << 12);
#pragma unroll
                for (int j = 0; j < 2; j++) {
                    const int kt = q * 2 + j;
                    const __bf16* reg = buf + (j << 11) + (cgl << 10);
                    bfv8 bv0 = *(const bfv8*)(reg + ((size_t)lane << 3));
                    bfv8 bv1 = *(const bfv8*)(reg + 512 + ((size_t)lane << 3));
                    acc[0] = __builtin_amdgcn_mfma_f32_16x16x32_bf16(afr2[kt], bv0, acc[0], 0, 0, 0);
                    acc[1] = __builtin_amdgcn_mfma_f32_16x16x32_bf16(afr2[kt], bv1, acc[1], 0, 0, 0);
                }
            }

            // bias (per output column)
#pragma unroll
            for (int r = 0; r < 4; r++) { acc[0][r] += b0; acc[1][r] += b1; }

            // gated fold. Gate table columns: a:0-15, b:16-31, s:32-55.
            if (st == 0)      { FOLD(0, 0);  FOLD(2, 32); }
            else if (st == 1) { FOLD(1, 16); FOLD(2, 40); }
            else              { FOLD(0, 8);  FOLD(1, 24); FOLD(2, 48); }
        }
    }
#undef FOLD

    // ---------------- epilogue: store 3 outputs (nontemporal) (R14) -----------
#pragma unroll
    for (int oi = 0; oi < 3; oi++) {
        float* ob = out + (size_t)oi * BATCH * DDIM;
#pragma unroll
        for (int r = 0; r < 4; r++) {
            int row = rbase + quad * 4 + r;
#pragma unroll
            for (int ntl = 0; ntl < 2; ntl++)
                __builtin_nontemporal_store(o[oi][ntl][r],
                    &ob[(size_t)row * DDIM + co * 64 + cgl * 32 + ntl * 16 + l16]);
        }
    }
}

extern "C" void kernel_launch(void* const* d_in, const int* in_sizes, int n_in,
                              void* d_out, int out_size, void* d_ws, size_t ws_size,
                              hipStream_t stream) {
    const float* xa = (const float*)d_in[0];
    const float* xb = (const float*)d_in[1];
    const float* xs = (const float*)d_in[2];
    const float* Wa = (const float*)d_in[3];
    const float* ba = (const float*)d_in[4];
    const float* Wb = (const float*)d_in[5];
    const float* bb = (const float*)d_in[6];
    const float* Ws = (const float*)d_in[7];
    const float* bs = (const float*)d_in[8];
    const float* Ga = (const float*)d_in[9];
    const float* Gb = (const float*)d_in[10];
    const float* Gs = (const float*)d_in[11];

    __bf16* wp = (__bf16*)d_ws;                 // 1.5 MB packed expert weights
    __bf16* gp = wp + 3 * 8 * 8 * 8 * 64 * 8;   // 32 KB packed gate matrix

    prep_kernel<<<200, 256, 0, stream>>>(Wa, Wb, Ws, Ga, Gb, Gs, wp, gp);
    ple_kernel<<<2 * (BATCH / ROWS), THREADS, 0, stream>>>(xa, xb, xs, ba, bb, bs, wp, gp, (float*)d_out);
}